// Round 1
// baseline (1430.989 us; speedup 1.0000x reference)
//
#include <hip/hip_runtime.h>

#define HD 128
#define NT 6

__device__ __forceinline__ float sigmoidf_(float x) {
  return 1.0f / (1.0f + __expf(-x));
}

// ================= Edge projection GEMM =================
// Computes 64x128 tile of  X @ W_edge[:, t*HD : (t+1)*HD] + b_edge[t*HD:...]
// ldP = HD (per-type buffer) or NT*HD (full P buffer, t = blockIdx.y)
__global__ __launch_bounds__(256) void k_gemm_edge(
    const float* __restrict__ X, const float* __restrict__ W,
    const float* __restrict__ B, float* __restrict__ P,
    int N, int ldP, int fixedType)
{
  __shared__ float Xs[64][132];   // +4 pad: row-group reads land on 2 banksets (free)
  __shared__ float Ws[64][128];   // K-chunk of 64 rows of W_t
  const int t = (fixedType >= 0) ? fixedType : (int)blockIdx.y;
  const int tid = threadIdx.x;
  const int row0 = blockIdx.x * 64;

  // stage X tile 64x128 (float4, coalesced)
  #pragma unroll
  for (int i = 0; i < 8; ++i) {
    int flat = i * 1024 + tid * 4;
    int r = flat >> 7, c = flat & 127;
    float4 v = make_float4(0.f, 0.f, 0.f, 0.f);
    if (row0 + r < N) v = *(const float4*)(X + (size_t)(row0 + r) * HD + c);
    *(float4*)&Xs[r][c] = v;
  }

  const int rg = tid >> 4;   // 16 row-groups x 4 rows
  const int cg = tid & 15;   // cols cg*4..+3 and 64+cg*4..+3 (2-way bank pattern = free)
  float acc[4][8];
  #pragma unroll
  for (int r = 0; r < 4; ++r)
    #pragma unroll
    for (int c = 0; c < 8; ++c) acc[r][c] = 0.f;

  const float* Wt = W + t * HD;          // W_edge row-major [HD][NT*HD]
  for (int kc = 0; kc < HD; kc += 64) {
    __syncthreads();
    #pragma unroll
    for (int i = 0; i < 8; ++i) {        // stage W chunk 64x128
      int flat = i * 1024 + tid * 4;
      int k = flat >> 7, j = flat & 127;
      *(float4*)&Ws[k][j] = *(const float4*)(Wt + (size_t)(kc + k) * (NT * HD) + j);
    }
    __syncthreads();
    #pragma unroll
    for (int k0 = 0; k0 < 64; k0 += 4) {
      float4 xv[4];
      #pragma unroll
      for (int r = 0; r < 4; ++r) xv[r] = *(const float4*)&Xs[rg * 4 + r][kc + k0];
      #pragma unroll
      for (int kk = 0; kk < 4; ++kk) {
        float4 wa = *(const float4*)&Ws[k0 + kk][cg * 4];
        float4 wb = *(const float4*)&Ws[k0 + kk][64 + cg * 4];
        #pragma unroll
        for (int r = 0; r < 4; ++r) {
          float x = (&xv[r].x)[kk];
          acc[r][0] = fmaf(x, wa.x, acc[r][0]);
          acc[r][1] = fmaf(x, wa.y, acc[r][1]);
          acc[r][2] = fmaf(x, wa.z, acc[r][2]);
          acc[r][3] = fmaf(x, wa.w, acc[r][3]);
          acc[r][4] = fmaf(x, wb.x, acc[r][4]);
          acc[r][5] = fmaf(x, wb.y, acc[r][5]);
          acc[r][6] = fmaf(x, wb.z, acc[r][6]);
          acc[r][7] = fmaf(x, wb.w, acc[r][7]);
        }
      }
    }
  }

  const float* Bt = B + t * HD;
  float4 b0 = *(const float4*)(Bt + cg * 4);
  float4 b1 = *(const float4*)(Bt + 64 + cg * 4);
  const int pOff = (ldP == HD) ? 0 : t * HD;
  #pragma unroll
  for (int r = 0; r < 4; ++r) {
    int row = row0 + rg * 4 + r;
    if (row < N) {
      float4 o0 = make_float4(acc[r][0] + b0.x, acc[r][1] + b0.y,
                              acc[r][2] + b0.z, acc[r][3] + b0.w);
      float4 o1 = make_float4(acc[r][4] + b1.x, acc[r][5] + b1.y,
                              acc[r][6] + b1.z, acc[r][7] + b1.w);
      *(float4*)(P + (size_t)row * ldP + pOff + cg * 4) = o0;
      *(float4*)(P + (size_t)row * ldP + pOff + 64 + cg * 4) = o1;
    }
  }
}

// ================= Edge scatter (atomic aggregate) =================
// wave-per-edge: lane i adds P[src, t*HD + 2i..2i+1] into agg[dest]
__global__ __launch_bounds__(256) void k_scatter(
    const float* __restrict__ P, const int* __restrict__ src,
    const int* __restrict__ dst, const int* __restrict__ typ,
    const int* __restrict__ nePtr, float* __restrict__ agg,
    int ldP, int fixedType)
{
  const int ne = nePtr[0];
  const int lane = threadIdx.x & 63;
  const int wid = (int)((blockIdx.x * blockDim.x + threadIdx.x) >> 6);
  const int nw = (int)((gridDim.x * blockDim.x) >> 6);
  for (int e = wid; e < ne; e += nw) {
    const int t = typ[e];                      // uniform -> scalar load
    if (fixedType >= 0 && t != fixedType) continue;
    const size_t po = (ldP == HD) ? (size_t)src[e] * HD
                                  : (size_t)src[e] * (NT * HD) + (size_t)t * HD;
    const float2 v = *(const float2*)(P + po + lane * 2);
    float* o = agg + (size_t)dst[e] * HD + lane * 2;
    unsafeAtomicAdd(o, v.x);       // global_atomic_add_f32
    unsafeAtomicAdd(o + 1, v.y);
  }
}

// ================= Fused GRU =================
// 32-row tile; pairs (W_ir,W_hr)->r, (W_iz,W_hz)->z, (W_in,W_hn)->out.
// Reads h=agg from HO, writes final output in place (rows are block-private).
__global__ __launch_bounds__(256) void k_gru(
    const float* __restrict__ X, float* __restrict__ HO,
    const float* __restrict__ Wir, const float* __restrict__ bir,
    const float* __restrict__ Wiz, const float* __restrict__ biz,
    const float* __restrict__ Win, const float* __restrict__ bin_,
    const float* __restrict__ Whr, const float* __restrict__ Whz,
    const float* __restrict__ Whn, const float* __restrict__ bhn,
    int N)
{
  __shared__ float Xs[32][132];
  __shared__ float Hs[32][132];
  __shared__ float Ws[2][32][128];   // (input-mat, hidden-mat) x K-chunk 32

  const int tid = threadIdx.x;
  const int row0 = blockIdx.x * 32;

  #pragma unroll
  for (int i = 0; i < 4; ++i) {
    int flat = i * 1024 + tid * 4;
    int r = flat >> 7, c = flat & 127;
    float4 vx = make_float4(0.f, 0.f, 0.f, 0.f), vh = vx;
    if (row0 + r < N) {
      vx = *(const float4*)(X + (size_t)(row0 + r) * HD + c);
      vh = *(const float4*)(HO + (size_t)(row0 + r) * HD + c);
    }
    *(float4*)&Xs[r][c] = vx;
    *(float4*)&Hs[r][c] = vh;
  }

  const int rg = tid >> 4;   // 16 groups x 2 rows
  const int cg = tid & 15;
  float rr[2][8], zz[2][8], aA[2][8], aB[2][8];

  #pragma unroll
  for (int p = 0; p < 3; ++p) {
    const float* WI = (p == 0) ? Wir : (p == 1) ? Wiz : Win;
    const float* WH = (p == 0) ? Whr : (p == 1) ? Whz : Whn;
    #pragma unroll
    for (int r = 0; r < 2; ++r)
      #pragma unroll
      for (int c = 0; c < 8; ++c) { aA[r][c] = 0.f; aB[r][c] = 0.f; }

    for (int kc = 0; kc < HD; kc += 32) {
      __syncthreads();
      #pragma unroll
      for (int i = 0; i < 8; ++i) {    // stage both mats' K-chunk
        int flat = i * 1024 + tid * 4;
        int m = flat >> 12;
        int rem = flat & 4095;
        int k = rem >> 7, j = rem & 127;
        const float* Wm = (m == 0) ? WI : WH;
        *(float4*)&Ws[m][k][j] = *(const float4*)(Wm + (size_t)(kc + k) * HD + j);
      }
      __syncthreads();
      #pragma unroll
      for (int k0 = 0; k0 < 32; k0 += 4) {
        float4 xv[2], hv[2];
        #pragma unroll
        for (int r = 0; r < 2; ++r) {
          xv[r] = *(const float4*)&Xs[rg * 2 + r][kc + k0];
          hv[r] = *(const float4*)&Hs[rg * 2 + r][kc + k0];
        }
        #pragma unroll
        for (int kk = 0; kk < 4; ++kk) {
          float4 wi0 = *(const float4*)&Ws[0][k0 + kk][cg * 4];
          float4 wi1 = *(const float4*)&Ws[0][k0 + kk][64 + cg * 4];
          float4 wh0 = *(const float4*)&Ws[1][k0 + kk][cg * 4];
          float4 wh1 = *(const float4*)&Ws[1][k0 + kk][64 + cg * 4];
          #pragma unroll
          for (int r = 0; r < 2; ++r) {
            float x = (&xv[r].x)[kk], h = (&hv[r].x)[kk];
            aA[r][0] = fmaf(x, wi0.x, aA[r][0]); aA[r][1] = fmaf(x, wi0.y, aA[r][1]);
            aA[r][2] = fmaf(x, wi0.z, aA[r][2]); aA[r][3] = fmaf(x, wi0.w, aA[r][3]);
            aA[r][4] = fmaf(x, wi1.x, aA[r][4]); aA[r][5] = fmaf(x, wi1.y, aA[r][5]);
            aA[r][6] = fmaf(x, wi1.z, aA[r][6]); aA[r][7] = fmaf(x, wi1.w, aA[r][7]);
            aB[r][0] = fmaf(h, wh0.x, aB[r][0]); aB[r][1] = fmaf(h, wh0.y, aB[r][1]);
            aB[r][2] = fmaf(h, wh0.z, aB[r][2]); aB[r][3] = fmaf(h, wh0.w, aB[r][3]);
            aB[r][4] = fmaf(h, wh1.x, aB[r][4]); aB[r][5] = fmaf(h, wh1.y, aB[r][5]);
            aB[r][6] = fmaf(h, wh1.z, aB[r][6]); aB[r][7] = fmaf(h, wh1.w, aB[r][7]);
          }
        }
      }
    }

    if (p < 2) {
      const float* bi = (p == 0) ? bir : biz;
      float4 bi0 = *(const float4*)(bi + cg * 4);
      float4 bi1 = *(const float4*)(bi + 64 + cg * 4);
      #pragma unroll
      for (int r = 0; r < 2; ++r)
        #pragma unroll
        for (int c = 0; c < 8; ++c) {
          float b = (c < 4) ? (&bi0.x)[c] : (&bi1.x)[c - 4];
          float v = sigmoidf_(aA[r][c] + b + aB[r][c]);
          if (p == 0) rr[r][c] = v; else zz[r][c] = v;
        }
    } else {
      float4 bn0 = *(const float4*)(bin_ + cg * 4);
      float4 bn1 = *(const float4*)(bin_ + 64 + cg * 4);
      float4 bh0 = *(const float4*)(bhn + cg * 4);
      float4 bh1 = *(const float4*)(bhn + 64 + cg * 4);
      #pragma unroll
      for (int r = 0; r < 2; ++r) {
        int row = row0 + rg * 2 + r;
        if (row < N) {
          float o[8];
          #pragma unroll
          for (int c = 0; c < 8; ++c) {
            float bn = (c < 4) ? (&bn0.x)[c] : (&bn1.x)[c - 4];
            float bh = (c < 4) ? (&bh0.x)[c] : (&bh1.x)[c - 4];
            int col = (c < 4) ? cg * 4 + c : 64 + cg * 4 + (c - 4);
            float nn = tanhf(aA[r][c] + bn + rr[r][c] * (aB[r][c] + bh));
            float h = Hs[rg * 2 + r][col];
            o[c] = (1.0f - zz[r][c]) * nn + zz[r][c] * h;
          }
          *(float4*)(HO + (size_t)row * HD + cg * 4) =
              make_float4(o[0], o[1], o[2], o[3]);
          *(float4*)(HO + (size_t)row * HD + 64 + cg * 4) =
              make_float4(o[4], o[5], o[6], o[7]);
        }
      }
    }
  }
}

extern "C" void kernel_launch(void* const* d_in, const int* in_sizes, int n_in,
                              void* d_out, int out_size, void* d_ws, size_t ws_size,
                              hipStream_t stream) {
  const float* X      = (const float*)d_in[0];
  const float* W_edge = (const float*)d_in[1];
  const float* b_edge = (const float*)d_in[2];
  const float* W_ir   = (const float*)d_in[3];
  const float* b_ir   = (const float*)d_in[4];
  const float* W_iz   = (const float*)d_in[5];
  const float* b_iz   = (const float*)d_in[6];
  const float* W_in   = (const float*)d_in[7];
  const float* b_in   = (const float*)d_in[8];
  const float* W_hr   = (const float*)d_in[9];
  const float* W_hz   = (const float*)d_in[10];
  const float* W_hn   = (const float*)d_in[11];
  const float* b_hn   = (const float*)d_in[12];
  const int* src      = (const int*)d_in[13];
  const int* dst      = (const int*)d_in[14];
  const int* typ      = (const int*)d_in[15];
  const int* nePtr    = (const int*)d_in[16];

  const int N = in_sizes[0] / HD;
  float* agg = (float*)d_out;          // aggregation accumulator lives in d_out
  float* P   = (float*)d_ws;

  hipMemsetAsync(d_out, 0, (size_t)out_size * sizeof(float), stream);

  const int gb = (N + 63) / 64;
  const size_t fullP = (size_t)N * NT * HD * sizeof(float);
  if (ws_size >= fullP) {
    // single-pass: P is [N, NT*HD]
    k_gemm_edge<<<dim3(gb, NT), 256, 0, stream>>>(X, W_edge, b_edge, P, N, NT * HD, -1);
    k_scatter<<<2048, 256, 0, stream>>>(P, src, dst, typ, nePtr, agg, NT * HD, -1);
  } else {
    // per-type loop: P is [N, HD] reused 6x (needs 51.2 MB ws)
    for (int t = 0; t < NT; ++t) {
      k_gemm_edge<<<dim3(gb, 1), 256, 0, stream>>>(X, W_edge, b_edge, P, N, HD, t);
      k_scatter<<<2048, 256, 0, stream>>>(P, src, dst, typ, nePtr, agg, HD, t);
    }
  }

  k_gru<<<(N + 31) / 32, 256, 0, stream>>>(X, agg, W_ir, b_ir, W_iz, b_iz,
                                           W_in, b_in, W_hr, W_hz, W_hn, b_hn, N);
}

// Round 2
// 714.433 us; speedup vs baseline: 2.0030x; 2.0030x over previous
//
#include <hip/hip_runtime.h>
#include <hip/hip_bf16.h>

#define HD 128
#define NT 6

typedef unsigned short u16;
typedef unsigned int u32;
typedef __attribute__((ext_vector_type(8))) short bf16x8;
typedef __attribute__((ext_vector_type(4))) float f32x4;

__device__ __forceinline__ float sigmoidf_(float x) {
  return 1.0f / (1.0f + __expf(-x));
}

// f32 -> bf16 (RNE)
__device__ __forceinline__ u16 f2bf(float x) {
  u32 u = __float_as_uint(x);
  return (u16)((u + 0x7FFFu + ((u >> 16) & 1u)) >> 16);
}

// XOR swizzle for 256B-row bf16 LDS tiles: spreads the 16B slot across banks.
// Involution; applied identically on write and read (rule: both sides).
__device__ __forceinline__ int swz(int p) { return p ^ (((p >> 8) & 7) << 4); }

// ============ weight convert+transpose: W^T bf16 ============
// WeT: [768][128] from W_edge [128][768]; WgT: 6x [128][128] (ir,iz,in,hr,hz,hn)
__global__ void k_cvt_w(const float* __restrict__ We,
                        const float* __restrict__ Wir, const float* __restrict__ Wiz,
                        const float* __restrict__ Win, const float* __restrict__ Whr,
                        const float* __restrict__ Whz, const float* __restrict__ Whn,
                        u16* __restrict__ WeT, u16* __restrict__ WgT) {
  int i = blockIdx.x * blockDim.x + threadIdx.x;
  if (i < NT * HD * HD) {
    int c = i >> 7, k = i & 127;                 // WeT[c][k] = We[k][c]
    WeT[i] = f2bf(We[(size_t)k * (NT * HD) + c]);
  } else {
    int j = i - NT * HD * HD;
    if (j < 6 * HD * HD) {
      int m = j >> 14, jj = j & 16383;
      int c = jj >> 7, k = jj & 127;
      const float* W = (m == 0) ? Wir : (m == 1) ? Wiz : (m == 2) ? Win
                     : (m == 3) ? Whr : (m == 4) ? Whz : Whn;
      WgT[j] = f2bf(W[(size_t)k * HD + c]);
    }
  }
}

// ============ Edge projection GEMM (bf16 MFMA) ============
// P[row, t*128+col] = bf16( X[row,:] @ W_edge[:, t*128+col] + b_edge )
__global__ __launch_bounds__(256) void k_gemm_edge(
    const float* __restrict__ X, const u16* __restrict__ WeT,
    const float* __restrict__ Be, u16* __restrict__ P,
    int N, int ldP, int fixedType)
{
  __shared__ char As[32768];   // 128 rows x 128 k bf16 (swizzled)
  __shared__ char Bs[32768];   // 128 cols x 128 k bf16 (swizzled)
  const int t = (fixedType >= 0) ? fixedType : (int)blockIdx.y;
  const int tid = threadIdx.x;
  const int row0 = blockIdx.x * 128;

  const char* gB = (const char*)(WeT + (size_t)t * HD * HD);  // contiguous 32KB
  #pragma unroll
  for (int i = 0; i < 8; ++i) {
    int p = i * 4096 + tid * 16;            // bf16-tile byte offset
    int row = row0 + (p >> 8);
    union { u16 u[8]; bf16x8 v; } ra;
    if (row < N) {
      const float4* s = (const float4*)(X + (size_t)row0 * HD + (p >> 1));
      float4 f0 = s[0], f1 = s[1];
      ra.u[0] = f2bf(f0.x); ra.u[1] = f2bf(f0.y); ra.u[2] = f2bf(f0.z); ra.u[3] = f2bf(f0.w);
      ra.u[4] = f2bf(f1.x); ra.u[5] = f2bf(f1.y); ra.u[6] = f2bf(f1.z); ra.u[7] = f2bf(f1.w);
    } else {
      #pragma unroll
      for (int j = 0; j < 8; ++j) ra.u[j] = 0;
    }
    *(bf16x8*)(As + swz(p)) = ra.v;
    *(bf16x8*)(Bs + swz(p)) = *(const bf16x8*)(gB + p);
  }
  __syncthreads();

  const int l = tid & 63, w = tid >> 6;
  const int m0 = (w >> 1) * 64, n0 = (w & 1) * 64;
  const int lr = l & 15, lg = l >> 4;

  f32x4 zero = {0.f, 0.f, 0.f, 0.f};
  f32x4 acc[4][4];
  #pragma unroll
  for (int m = 0; m < 4; ++m)
    #pragma unroll
    for (int n = 0; n < 4; ++n) acc[m][n] = zero;

  #pragma unroll
  for (int k = 0; k < 4; ++k) {
    bf16x8 a[4], b[4];
    #pragma unroll
    for (int m = 0; m < 4; ++m) {
      int addr = (m0 + m * 16 + lr) * 256 + k * 64 + lg * 16;
      a[m] = *(const bf16x8*)(As + swz(addr));
    }
    #pragma unroll
    for (int n = 0; n < 4; ++n) {
      int addr = (n0 + n * 16 + lr) * 256 + k * 64 + lg * 16;
      b[n] = *(const bf16x8*)(Bs + swz(addr));
    }
    #pragma unroll
    for (int m = 0; m < 4; ++m)
      #pragma unroll
      for (int n = 0; n < 4; ++n)
        acc[m][n] = __builtin_amdgcn_mfma_f32_16x16x32_bf16(a[m], b[n], acc[m][n], 0, 0, 0);
  }

  float bias[4];
  #pragma unroll
  for (int n = 0; n < 4; ++n) bias[n] = Be[t * HD + n0 + n * 16 + lr];
  const int pOff = (ldP == HD) ? 0 : t * HD;
  #pragma unroll
  for (int m = 0; m < 4; ++m) {
    int rbase = row0 + m0 + m * 16 + lg * 4;
    #pragma unroll
    for (int j = 0; j < 4; ++j) {
      int row = rbase + j;
      if (row < N) {
        #pragma unroll
        for (int n = 0; n < 4; ++n)
          P[(size_t)row * ldP + pOff + n0 + n * 16 + lr] = f2bf(acc[m][n][j] + bias[n]);
      }
    }
  }
}

// ============ Edge scatter (bf16 gather, f32 atomics) ============
__global__ __launch_bounds__(256) void k_scatter(
    const u16* __restrict__ P, const int* __restrict__ src,
    const int* __restrict__ dst, const int* __restrict__ typ,
    const int* __restrict__ nePtr, float* __restrict__ agg,
    int ldP, int fixedType)
{
  const int ne = nePtr[0];
  const int lane = threadIdx.x & 63;
  const int wid = (int)((blockIdx.x * blockDim.x + threadIdx.x) >> 6);
  const int nw = (int)((gridDim.x * blockDim.x) >> 6);
  for (int e = wid; e < ne; e += nw) {
    const int t = typ[e];
    if (fixedType >= 0 && t != fixedType) continue;
    const size_t po = (ldP == HD) ? (size_t)src[e] * HD
                                  : (size_t)src[e] * (NT * HD) + (size_t)t * HD;
    u32 v = *(const u32*)(P + po + lane * 2);
    float x0 = __uint_as_float(v << 16);
    float x1 = __uint_as_float(v & 0xffff0000u);
    float* o = agg + (size_t)dst[e] * HD + lane * 2;
    unsafeAtomicAdd(o, x0);
    unsafeAtomicAdd(o + 1, x1);
  }
}

// ============ Fused GRU (bf16 MFMA) ============
// out = (1-z)*tanh(xWin+bin + r*(hWhn+bhn)) + z*h ; in-place over agg (=out).
__global__ __launch_bounds__(256) void k_gru(
    const float* __restrict__ X, const float* __restrict__ agg,
    const u16* __restrict__ WgT,   // 6x[128][128] transposed: ir,iz,in,hr,hz,hn
    const float* __restrict__ bir, const float* __restrict__ biz,
    const float* __restrict__ bin_, const float* __restrict__ bhn,
    float* __restrict__ out, int N)
{
  __shared__ char Xs[16384];   // 64 rows x 128 k bf16 (swizzled)
  __shared__ char Hs[16384];
  const int tid = threadIdx.x;
  const int row0 = blockIdx.x * 64;

  #pragma unroll
  for (int i = 0; i < 4; ++i) {
    int p = i * 4096 + tid * 16;
    int row = row0 + (p >> 8);
    union { u16 u[8]; bf16x8 v; } rx, rh;
    if (row < N) {
      const float4* sx = (const float4*)(X + (size_t)row0 * HD + (p >> 1));
      const float4* sh = (const float4*)(agg + (size_t)row0 * HD + (p >> 1));
      float4 x0 = sx[0], x1 = sx[1], h0 = sh[0], h1 = sh[1];
      rx.u[0] = f2bf(x0.x); rx.u[1] = f2bf(x0.y); rx.u[2] = f2bf(x0.z); rx.u[3] = f2bf(x0.w);
      rx.u[4] = f2bf(x1.x); rx.u[5] = f2bf(x1.y); rx.u[6] = f2bf(x1.z); rx.u[7] = f2bf(x1.w);
      rh.u[0] = f2bf(h0.x); rh.u[1] = f2bf(h0.y); rh.u[2] = f2bf(h0.z); rh.u[3] = f2bf(h0.w);
      rh.u[4] = f2bf(h1.x); rh.u[5] = f2bf(h1.y); rh.u[6] = f2bf(h1.z); rh.u[7] = f2bf(h1.w);
    } else {
      #pragma unroll
      for (int j = 0; j < 8; ++j) { rx.u[j] = 0; rh.u[j] = 0; }
    }
    *(bf16x8*)(Xs + swz(p)) = rx.v;
    *(bf16x8*)(Hs + swz(p)) = rh.v;
  }
  __syncthreads();

  const int l = tid & 63, w = tid >> 6;
  const int lr = l & 15, lg = l >> 4;
  const int rloc = w * 16;

  f32x4 zero = {0.f, 0.f, 0.f, 0.f};
  auto sweep = [&](const char* Ab, const u16* WT, f32x4* acc) {
    #pragma unroll
    for (int n = 0; n < 8; ++n) acc[n] = zero;
    #pragma unroll
    for (int k = 0; k < 4; ++k) {
      int addr = (rloc + lr) * 256 + k * 64 + lg * 16;
      bf16x8 a = *(const bf16x8*)(Ab + swz(addr));
      #pragma unroll
      for (int n = 0; n < 8; ++n) {
        bf16x8 b = *(const bf16x8*)(WT + (size_t)(n * 16 + lr) * HD + k * 32 + lg * 8);
        acc[n] = __builtin_amdgcn_mfma_f32_16x16x32_bf16(a, b, acc[n], 0, 0, 0);
      }
    }
  };

  f32x4 t1[8], t2[8], rg[8], nn[8];
  float bv[8];

  // r = sigmoid(xWir + bir + hWhr)
  sweep(Xs, WgT + 0 * HD * HD, t1);
  sweep(Hs, WgT + 3 * HD * HD, t2);
  #pragma unroll
  for (int n = 0; n < 8; ++n) bv[n] = bir[n * 16 + lr];
  #pragma unroll
  for (int n = 0; n < 8; ++n)
    #pragma unroll
    for (int j = 0; j < 4; ++j) rg[n][j] = sigmoidf_(t1[n][j] + bv[n] + t2[n][j]);

  // rn = r * (hWhn + bhn)
  sweep(Hs, WgT + 5 * HD * HD, t2);
  #pragma unroll
  for (int n = 0; n < 8; ++n) bv[n] = bhn[n * 16 + lr];
  #pragma unroll
  for (int n = 0; n < 8; ++n)
    #pragma unroll
    for (int j = 0; j < 4; ++j) rg[n][j] *= (t2[n][j] + bv[n]);

  // n = tanh(xWin + bin + rn)
  sweep(Xs, WgT + 2 * HD * HD, t1);
  #pragma unroll
  for (int n = 0; n < 8; ++n) bv[n] = bin_[n * 16 + lr];
  #pragma unroll
  for (int n = 0; n < 8; ++n)
    #pragma unroll
    for (int j = 0; j < 4; ++j) nn[n][j] = tanhf(t1[n][j] + bv[n] + rg[n][j]);

  // z = sigmoid(xWiz + biz + hWhz); out = (1-z)*n + z*h
  sweep(Xs, WgT + 1 * HD * HD, t1);
  sweep(Hs, WgT + 4 * HD * HD, t2);
  #pragma unroll
  for (int n = 0; n < 8; ++n) bv[n] = biz[n * 16 + lr];
  #pragma unroll
  for (int n = 0; n < 8; ++n) {
    #pragma unroll
    for (int j = 0; j < 4; ++j) {
      int row = row0 + rloc + lg * 4 + j;
      if (row < N) {
        float z = sigmoidf_(t1[n][j] + bv[n] + t2[n][j]);
        float h = agg[(size_t)row * HD + n * 16 + lr];
        out[(size_t)row * HD + n * 16 + lr] = (1.0f - z) * nn[n][j] + z * h;
      }
    }
  }
}

extern "C" void kernel_launch(void* const* d_in, const int* in_sizes, int n_in,
                              void* d_out, int out_size, void* d_ws, size_t ws_size,
                              hipStream_t stream) {
  const float* X      = (const float*)d_in[0];
  const float* W_edge = (const float*)d_in[1];
  const float* b_edge = (const float*)d_in[2];
  const float* W_ir   = (const float*)d_in[3];
  const float* b_ir   = (const float*)d_in[4];
  const float* W_iz   = (const float*)d_in[5];
  const float* b_iz   = (const float*)d_in[6];
  const float* W_in   = (const float*)d_in[7];
  const float* b_in   = (const float*)d_in[8];
  const float* W_hr   = (const float*)d_in[9];
  const float* W_hz   = (const float*)d_in[10];
  const float* W_hn   = (const float*)d_in[11];
  const float* b_hn   = (const float*)d_in[12];
  const int* src      = (const int*)d_in[13];
  const int* dst      = (const int*)d_in[14];
  const int* typ      = (const int*)d_in[15];
  const int* nePtr    = (const int*)d_in[16];

  const int N = in_sizes[0] / HD;
  float* agg = (float*)d_out;
  char* ws = (char*)d_ws;

  size_t off = 0;
  u16* WeT = (u16*)(ws + off); off += (size_t)NT * HD * HD * 2;
  u16* WgT = (u16*)(ws + off); off += (size_t)6 * HD * HD * 2;
  off = (off + 255) & ~(size_t)255;
  u16* P = (u16*)(ws + off);
  const size_t fullP = (size_t)N * NT * HD * 2;
  const bool full = ws_size >= off + fullP;

  hipMemsetAsync(d_out, 0, (size_t)out_size * sizeof(float), stream);

  int cvtThreads = NT * HD * HD + 6 * HD * HD;
  k_cvt_w<<<(cvtThreads + 255) / 256, 256, 0, stream>>>(
      W_edge, W_ir, W_iz, W_in, W_hr, W_hz, W_hn, WeT, WgT);

  const int gb = (N + 127) / 128;
  if (full) {
    k_gemm_edge<<<dim3(gb, NT), 256, 0, stream>>>(X, WeT, b_edge, P, N, NT * HD, -1);
    k_scatter<<<2048, 256, 0, stream>>>(P, src, dst, typ, nePtr, agg, NT * HD, -1);
  } else {
    for (int t = 0; t < NT; ++t) {
      k_gemm_edge<<<dim3(gb, 1), 256, 0, stream>>>(X, WeT, b_edge, P, N, HD, t);
      k_scatter<<<2048, 256, 0, stream>>>(P, src, dst, typ, nePtr, agg, HD, t);
    }
  }

  k_gru<<<(N + 63) / 64, 256, 0, stream>>>(X, agg, WgT, b_ir, b_iz, b_in, b_hn, agg, N);
}

// Round 3
// 628.257 us; speedup vs baseline: 2.2777x; 1.1372x over previous
//
#include <hip/hip_runtime.h>
#include <hip/hip_bf16.h>

#define HD 128
#define NT 6

typedef unsigned short u16;
typedef unsigned int u32;
typedef __attribute__((ext_vector_type(8))) short bf16x8;
typedef __attribute__((ext_vector_type(4))) float f32x4;

__device__ __forceinline__ float sigmoidf_(float x) {
  return 1.0f / (1.0f + __expf(-x));
}

// f32 -> bf16 (RNE)
__device__ __forceinline__ u16 f2bf(float x) {
  u32 u = __float_as_uint(x);
  return (u16)((u + 0x7FFFu + ((u >> 16) & 1u)) >> 16);
}

// XOR swizzle for 256B-row bf16 LDS tiles (involution, both sides).
// Only bits [4..6] are XORed -> any access granularity works with full-offset swz.
__device__ __forceinline__ int swz(int p) { return p ^ (((p >> 8) & 7) << 4); }

// ============ weight convert+transpose: W^T bf16 ============
__global__ void k_cvt_w(const float* __restrict__ We,
                        const float* __restrict__ Wir, const float* __restrict__ Wiz,
                        const float* __restrict__ Win, const float* __restrict__ Whr,
                        const float* __restrict__ Whz, const float* __restrict__ Whn,
                        u16* __restrict__ WeT, u16* __restrict__ WgT) {
  int i = blockIdx.x * blockDim.x + threadIdx.x;
  if (i < NT * HD * HD) {
    int c = i >> 7, k = i & 127;                 // WeT[c][k] = We[k][c]
    WeT[i] = f2bf(We[(size_t)k * (NT * HD) + c]);
  } else {
    int j = i - NT * HD * HD;
    if (j < 6 * HD * HD) {
      int m = j >> 14, jj = j & 16383;
      int c = jj >> 7, k = jj & 127;
      const float* W = (m == 0) ? Wir : (m == 1) ? Wiz : (m == 2) ? Win
                     : (m == 3) ? Whr : (m == 4) ? Whz : Whn;
      WgT[j] = f2bf(W[(size_t)k * HD + c]);
    }
  }
}

// ============ Edge projection GEMM (bf16 MFMA) ============
__global__ __launch_bounds__(256) void k_gemm_edge(
    const float* __restrict__ X, const u16* __restrict__ WeT,
    const float* __restrict__ Be, u16* __restrict__ P,
    int N, int ldP, int fixedType)
{
  __shared__ char As[32768];   // 128 rows x 128 k bf16 (swizzled)
  __shared__ char Bs[32768];
  const int t = (fixedType >= 0) ? fixedType : (int)blockIdx.y;
  const int tid = threadIdx.x;
  const int row0 = blockIdx.x * 128;

  const char* gB = (const char*)(WeT + (size_t)t * HD * HD);
  #pragma unroll
  for (int i = 0; i < 8; ++i) {
    int p = i * 4096 + tid * 16;
    int row = row0 + (p >> 8);
    union { u16 u[8]; bf16x8 v; } ra;
    if (row < N) {
      const float4* s = (const float4*)(X + (size_t)row0 * HD + (p >> 1));
      float4 f0 = s[0], f1 = s[1];
      ra.u[0] = f2bf(f0.x); ra.u[1] = f2bf(f0.y); ra.u[2] = f2bf(f0.z); ra.u[3] = f2bf(f0.w);
      ra.u[4] = f2bf(f1.x); ra.u[5] = f2bf(f1.y); ra.u[6] = f2bf(f1.z); ra.u[7] = f2bf(f1.w);
    } else {
      #pragma unroll
      for (int j = 0; j < 8; ++j) ra.u[j] = 0;
    }
    *(bf16x8*)(As + swz(p)) = ra.v;
    *(bf16x8*)(Bs + swz(p)) = *(const bf16x8*)(gB + p);
  }
  __syncthreads();

  const int l = tid & 63, w = tid >> 6;
  const int m0 = (w >> 1) * 64, n0 = (w & 1) * 64;
  const int lr = l & 15, lg = l >> 4;

  f32x4 zero = {0.f, 0.f, 0.f, 0.f};
  f32x4 acc[4][4];
  #pragma unroll
  for (int m = 0; m < 4; ++m)
    #pragma unroll
    for (int n = 0; n < 4; ++n) acc[m][n] = zero;

  #pragma unroll
  for (int k = 0; k < 4; ++k) {
    bf16x8 a[4], b[4];
    #pragma unroll
    for (int m = 0; m < 4; ++m)
      a[m] = *(const bf16x8*)(As + swz((m0 + m * 16 + lr) * 256 + k * 64 + lg * 16));
    #pragma unroll
    for (int n = 0; n < 4; ++n)
      b[n] = *(const bf16x8*)(Bs + swz((n0 + n * 16 + lr) * 256 + k * 64 + lg * 16));
    #pragma unroll
    for (int m = 0; m < 4; ++m)
      #pragma unroll
      for (int n = 0; n < 4; ++n)
        acc[m][n] = __builtin_amdgcn_mfma_f32_16x16x32_bf16(a[m], b[n], acc[m][n], 0, 0, 0);
  }

  float bias[4];
  #pragma unroll
  for (int n = 0; n < 4; ++n) bias[n] = Be[t * HD + n0 + n * 16 + lr];
  const int pOff = (ldP == HD) ? 0 : t * HD;
  #pragma unroll
  for (int m = 0; m < 4; ++m) {
    int rbase = row0 + m0 + m * 16 + lg * 4;
    #pragma unroll
    for (int j = 0; j < 4; ++j) {
      int row = rbase + j;
      if (row < N) {
        #pragma unroll
        for (int n = 0; n < 4; ++n)
          P[(size_t)row * ldP + pOff + n0 + n * 16 + lr] = f2bf(acc[m][n][j] + bias[n]);
      }
    }
  }
}

// ============ CSR build ============
__global__ __launch_bounds__(256) void k_count(const int* __restrict__ dst,
                                               const int* __restrict__ nePtr,
                                               int* __restrict__ deg) {
  const int ne = nePtr[0];
  for (int e = blockIdx.x * blockDim.x + threadIdx.x; e < ne;
       e += gridDim.x * blockDim.x)
    atomicAdd(&deg[dst[e]], 1);
}

__global__ __launch_bounds__(256) void k_scan_a(const int* __restrict__ deg,
                                                int* __restrict__ off,
                                                int* __restrict__ bsum, int N) {
  __shared__ int s[256];
  const int b = blockIdx.x, tid = threadIdx.x;
  const int base = b * 1024 + tid * 4;
  int v0 = 0, v1 = 0, v2 = 0, v3 = 0;
  if (base < N) v0 = deg[base];
  if (base + 1 < N) v1 = deg[base + 1];
  if (base + 2 < N) v2 = deg[base + 2];
  if (base + 3 < N) v3 = deg[base + 3];
  const int sum = v0 + v1 + v2 + v3;
  s[tid] = sum;
  __syncthreads();
  for (int d = 1; d < 256; d <<= 1) {
    int t = (tid >= d) ? s[tid - d] : 0;
    __syncthreads();
    s[tid] += t;
    __syncthreads();
  }
  const int excl = s[tid] - sum;
  if (base < N) off[base] = excl;
  if (base + 1 < N) off[base + 1] = excl + v0;
  if (base + 2 < N) off[base + 2] = excl + v0 + v1;
  if (base + 3 < N) off[base + 3] = excl + v0 + v1 + v2;
  if (tid == 255) bsum[b] = s[255];
}

__global__ void k_scan_b(int* __restrict__ bsum, int nb) {
  __shared__ int s[1024];
  const int tid = threadIdx.x;
  const int v = (tid < nb) ? bsum[tid] : 0;
  s[tid] = v;
  __syncthreads();
  for (int d = 1; d < 1024; d <<= 1) {
    int t = (tid >= d) ? s[tid - d] : 0;
    __syncthreads();
    s[tid] += t;
    __syncthreads();
  }
  if (tid < nb) bsum[tid] = s[tid] - v;   // exclusive
}

__global__ __launch_bounds__(256) void k_scan_c(int* __restrict__ off,
                                                const int* __restrict__ bsum, int N) {
  const int b = blockIdx.x, tid = threadIdx.x;
  const int add = bsum[b];
  const int base = b * 1024 + tid * 4;
  #pragma unroll
  for (int i = 0; i < 4; ++i)
    if (base + i < N) off[base + i] += add;
}

// fill: pos via atomic on off (off[n] becomes END afterwards)
__global__ __launch_bounds__(256) void k_fill(const int* __restrict__ src,
                                              const int* __restrict__ dst,
                                              const int* __restrict__ typ,
                                              const int* __restrict__ nePtr,
                                              int* __restrict__ off,
                                              u32* __restrict__ elist) {
  const int ne = nePtr[0];
  for (int e = blockIdx.x * blockDim.x + threadIdx.x; e < ne;
       e += gridDim.x * blockDim.x) {
    int pos = atomicAdd(&off[dst[e]], 1);
    elist[pos] = (u32)(src[e] * NT + typ[e]);   // P-row index
  }
}

// ============ Fused gather + GRU (bf16 MFMA, no barriers) ============
__global__ __launch_bounds__(256) void k_gather_gru(
    const float* __restrict__ X, const u16* __restrict__ P,
    const int* __restrict__ deg, const int* __restrict__ off,
    const u32* __restrict__ elist, const u16* __restrict__ WgT,
    const float* __restrict__ bir, const float* __restrict__ biz,
    const float* __restrict__ bin_, const float* __restrict__ bhn,
    float* __restrict__ out, int N)
{
  __shared__ char Xs[16384];   // 64 rows x 128 k bf16 (swizzled), wave-private quarters
  __shared__ char Hs[16384];
  const int tid = threadIdx.x;
  const int l = tid & 63, w = tid >> 6;
  const int row0 = blockIdx.x * 64;
  const int wr0 = w * 16;                 // wave's first local row

  // --- stage X rows (wave-local: 16 rows x 16 segs of 16B) ---
  #pragma unroll
  for (int it = 0; it < 4; ++it) {
    int chunk = it * 64 + l;
    int r = chunk >> 4, seg = chunk & 15;
    int grow = row0 + wr0 + r;
    union { u16 u[8]; bf16x8 v; } rx;
    if (grow < N) {
      const float4* sx = (const float4*)(X + (size_t)grow * HD + seg * 8);
      float4 x0 = sx[0], x1 = sx[1];
      rx.u[0] = f2bf(x0.x); rx.u[1] = f2bf(x0.y); rx.u[2] = f2bf(x0.z); rx.u[3] = f2bf(x0.w);
      rx.u[4] = f2bf(x1.x); rx.u[5] = f2bf(x1.y); rx.u[6] = f2bf(x1.z); rx.u[7] = f2bf(x1.w);
    } else {
      #pragma unroll
      for (int j = 0; j < 8; ++j) rx.u[j] = 0;
    }
    *(bf16x8*)(Xs + swz((wr0 + r) * 256 + seg * 16)) = rx.v;
  }

  // --- gather h rows from P via CSR (f32 accum, 2 cols/lane) ---
  for (int i = 0; i < 16; ++i) {
    int n = row0 + wr0 + i;
    float a0 = 0.f, a1 = 0.f;
    if (n < N) {
      int e1 = off[n];            // post-fill = end
      int e0 = e1 - deg[n];
      for (int e = e0; e < e1; ++e) {
        u32 pk = elist[e];
        u32 v = *((const u32*)(P + (size_t)pk * HD) + l);
        a0 += __uint_as_float(v << 16);
        a1 += __uint_as_float(v & 0xffff0000u);
      }
    }
    u32 hp = ((u32)f2bf(a1) << 16) | (u32)f2bf(a0);
    *(u32*)(Hs + swz((wr0 + i) * 256 + l * 4)) = hp;
  }

  const int lr = l & 15, lg = l >> 4;
  const int rloc = wr0;

  f32x4 zero = {0.f, 0.f, 0.f, 0.f};
  auto sweep = [&](const char* Ab, const u16* WT, f32x4* acc) {
    #pragma unroll
    for (int n = 0; n < 8; ++n) acc[n] = zero;
    #pragma unroll
    for (int k = 0; k < 4; ++k) {
      bf16x8 a = *(const bf16x8*)(Ab + swz((rloc + lr) * 256 + k * 64 + lg * 16));
      #pragma unroll
      for (int n = 0; n < 8; ++n) {
        bf16x8 b = *(const bf16x8*)(WT + (size_t)(n * 16 + lr) * HD + k * 32 + lg * 8);
        acc[n] = __builtin_amdgcn_mfma_f32_16x16x32_bf16(a, b, acc[n], 0, 0, 0);
      }
    }
  };

  f32x4 t1[8], t2[8], rg[8], nn[8];
  float bv[8];

  sweep(Xs, WgT + 0 * HD * HD, t1);            // xWir
  sweep(Hs, WgT + 3 * HD * HD, t2);            // hWhr
  #pragma unroll
  for (int n = 0; n < 8; ++n) bv[n] = bir[n * 16 + lr];
  #pragma unroll
  for (int n = 0; n < 8; ++n)
    #pragma unroll
    for (int j = 0; j < 4; ++j) rg[n][j] = sigmoidf_(t1[n][j] + bv[n] + t2[n][j]);

  sweep(Hs, WgT + 5 * HD * HD, t2);            // hWhn
  #pragma unroll
  for (int n = 0; n < 8; ++n) bv[n] = bhn[n * 16 + lr];
  #pragma unroll
  for (int n = 0; n < 8; ++n)
    #pragma unroll
    for (int j = 0; j < 4; ++j) rg[n][j] *= (t2[n][j] + bv[n]);

  sweep(Xs, WgT + 2 * HD * HD, t1);            // xWin
  #pragma unroll
  for (int n = 0; n < 8; ++n) bv[n] = bin_[n * 16 + lr];
  #pragma unroll
  for (int n = 0; n < 8; ++n)
    #pragma unroll
    for (int j = 0; j < 4; ++j) nn[n][j] = tanhf(t1[n][j] + bv[n] + rg[n][j]);

  sweep(Xs, WgT + 1 * HD * HD, t1);            // xWiz
  sweep(Hs, WgT + 4 * HD * HD, t2);            // hWhz
  #pragma unroll
  for (int n = 0; n < 8; ++n) bv[n] = biz[n * 16 + lr];
  #pragma unroll
  for (int n = 0; n < 8; ++n) {
    #pragma unroll
    for (int j = 0; j < 4; ++j) {
      int row = row0 + rloc + lg * 4 + j;
      if (row < N) {
        float z = sigmoidf_(t1[n][j] + bv[n] + t2[n][j]);
        u16 hu = *(const u16*)(Hs + swz((rloc + lg * 4 + j) * 256 + (n * 16 + lr) * 2));
        float h = __uint_as_float((u32)hu << 16);
        out[(size_t)row * HD + n * 16 + lr] = (1.0f - z) * nn[n][j] + z * h;
      }
    }
  }
}

// ============ Fallback: atomic scatter + standalone GRU ============
__global__ __launch_bounds__(256) void k_scatter(
    const u16* __restrict__ P, const int* __restrict__ src,
    const int* __restrict__ dst, const int* __restrict__ typ,
    const int* __restrict__ nePtr, float* __restrict__ agg,
    int ldP, int fixedType)
{
  const int ne = nePtr[0];
  const int lane = threadIdx.x & 63;
  const int wid = (int)((blockIdx.x * blockDim.x + threadIdx.x) >> 6);
  const int nw = (int)((gridDim.x * blockDim.x) >> 6);
  for (int e = wid; e < ne; e += nw) {
    const int t = typ[e];
    if (fixedType >= 0 && t != fixedType) continue;
    const size_t po = (ldP == HD) ? (size_t)src[e] * HD
                                  : (size_t)src[e] * (NT * HD) + (size_t)t * HD;
    u32 v = *(const u32*)(P + po + lane * 2);
    float* o = agg + (size_t)dst[e] * HD + lane * 2;
    unsafeAtomicAdd(o, __uint_as_float(v << 16));
    unsafeAtomicAdd(o + 1, __uint_as_float(v & 0xffff0000u));
  }
}

__global__ __launch_bounds__(256) void k_gru(
    const float* __restrict__ X, const float* __restrict__ agg,
    const u16* __restrict__ WgT,
    const float* __restrict__ bir, const float* __restrict__ biz,
    const float* __restrict__ bin_, const float* __restrict__ bhn,
    float* __restrict__ out, int N)
{
  __shared__ char Xs[16384];
  __shared__ char Hs[16384];
  const int tid = threadIdx.x;
  const int row0 = blockIdx.x * 64;

  #pragma unroll
  for (int i = 0; i < 4; ++i) {
    int p = i * 4096 + tid * 16;
    int row = row0 + (p >> 8);
    union { u16 u[8]; bf16x8 v; } rx, rh;
    if (row < N) {
      const float4* sx = (const float4*)(X + (size_t)row0 * HD + (p >> 1));
      const float4* sh = (const float4*)(agg + (size_t)row0 * HD + (p >> 1));
      float4 x0 = sx[0], x1 = sx[1], h0 = sh[0], h1 = sh[1];
      rx.u[0] = f2bf(x0.x); rx.u[1] = f2bf(x0.y); rx.u[2] = f2bf(x0.z); rx.u[3] = f2bf(x0.w);
      rx.u[4] = f2bf(x1.x); rx.u[5] = f2bf(x1.y); rx.u[6] = f2bf(x1.z); rx.u[7] = f2bf(x1.w);
      rh.u[0] = f2bf(h0.x); rh.u[1] = f2bf(h0.y); rh.u[2] = f2bf(h0.z); rh.u[3] = f2bf(h0.w);
      rh.u[4] = f2bf(h1.x); rh.u[5] = f2bf(h1.y); rh.u[6] = f2bf(h1.z); rh.u[7] = f2bf(h1.w);
    } else {
      #pragma unroll
      for (int j = 0; j < 8; ++j) { rx.u[j] = 0; rh.u[j] = 0; }
    }
    *(bf16x8*)(Xs + swz(p)) = rx.v;
    *(bf16x8*)(Hs + swz(p)) = rh.v;
  }
  __syncthreads();

  const int l = tid & 63, w = tid >> 6;
  const int lr = l & 15, lg = l >> 4;
  const int rloc = w * 16;

  f32x4 zero = {0.f, 0.f, 0.f, 0.f};
  auto sweep = [&](const char* Ab, const u16* WT, f32x4* acc) {
    #pragma unroll
    for (int n = 0; n < 8; ++n) acc[n] = zero;
    #pragma unroll
    for (int k = 0; k < 4; ++k) {
      bf16x8 a = *(const bf16x8*)(Ab + swz((rloc + lr) * 256 + k * 64 + lg * 16));
      #pragma unroll
      for (int n = 0; n < 8; ++n) {
        bf16x8 b = *(const bf16x8*)(WT + (size_t)(n * 16 + lr) * HD + k * 32 + lg * 8);
        acc[n] = __builtin_amdgcn_mfma_f32_16x16x32_bf16(a, b, acc[n], 0, 0, 0);
      }
    }
  };

  f32x4 t1[8], t2[8], rg[8], nn[8];
  float bv[8];

  sweep(Xs, WgT + 0 * HD * HD, t1);
  sweep(Hs, WgT + 3 * HD * HD, t2);
  #pragma unroll
  for (int n = 0; n < 8; ++n) bv[n] = bir[n * 16 + lr];
  #pragma unroll
  for (int n = 0; n < 8; ++n)
    #pragma unroll
    for (int j = 0; j < 4; ++j) rg[n][j] = sigmoidf_(t1[n][j] + bv[n] + t2[n][j]);

  sweep(Hs, WgT + 5 * HD * HD, t2);
  #pragma unroll
  for (int n = 0; n < 8; ++n) bv[n] = bhn[n * 16 + lr];
  #pragma unroll
  for (int n = 0; n < 8; ++n)
    #pragma unroll
    for (int j = 0; j < 4; ++j) rg[n][j] *= (t2[n][j] + bv[n]);

  sweep(Xs, WgT + 2 * HD * HD, t1);
  #pragma unroll
  for (int n = 0; n < 8; ++n) bv[n] = bin_[n * 16 + lr];
  #pragma unroll
  for (int n = 0; n < 8; ++n)
    #pragma unroll
    for (int j = 0; j < 4; ++j) nn[n][j] = tanhf(t1[n][j] + bv[n] + rg[n][j]);

  sweep(Xs, WgT + 1 * HD * HD, t1);
  sweep(Hs, WgT + 4 * HD * HD, t2);
  #pragma unroll
  for (int n = 0; n < 8; ++n) bv[n] = biz[n * 16 + lr];
  #pragma unroll
  for (int n = 0; n < 8; ++n) {
    #pragma unroll
    for (int j = 0; j < 4; ++j) {
      int row = row0 + rloc + lg * 4 + j;
      if (row < N) {
        float z = sigmoidf_(t1[n][j] + bv[n] + t2[n][j]);
        float h = agg[(size_t)row * HD + n * 16 + lr];
        out[(size_t)row * HD + n * 16 + lr] = (1.0f - z) * nn[n][j] + z * h;
      }
    }
  }
}

extern "C" void kernel_launch(void* const* d_in, const int* in_sizes, int n_in,
                              void* d_out, int out_size, void* d_ws, size_t ws_size,
                              hipStream_t stream) {
  const float* X      = (const float*)d_in[0];
  const float* W_edge = (const float*)d_in[1];
  const float* b_edge = (const float*)d_in[2];
  const float* b_ir   = (const float*)d_in[4];
  const float* b_iz   = (const float*)d_in[6];
  const float* b_in   = (const float*)d_in[8];
  const float* b_hn   = (const float*)d_in[12];
  const int* src      = (const int*)d_in[13];
  const int* dst      = (const int*)d_in[14];
  const int* typ      = (const int*)d_in[15];
  const int* nePtr    = (const int*)d_in[16];

  const int N = in_sizes[0] / HD;
  const int E = in_sizes[13];
  char* ws = (char*)d_ws;

  size_t cur = 0;
  auto alloc = [&](size_t bytes) {
    size_t p = cur;
    cur = (cur + bytes + 255) & ~(size_t)255;
    return p;
  };
  u16* WeT   = (u16*)(ws + alloc((size_t)NT * HD * HD * 2));
  u16* WgT   = (u16*)(ws + alloc((size_t)6 * HD * HD * 2));
  int* deg   = (int*)(ws + alloc((size_t)N * 4));
  int* offA  = (int*)(ws + alloc((size_t)N * 4));
  int* bsum  = (int*)(ws + alloc(1024 * 4));
  u32* elist = (u32*)(ws + alloc((size_t)E * 4));
  size_t base_need = cur;
  u16* P     = (u16*)(ws + alloc((size_t)N * NT * HD * 2));
  const size_t csr_need = cur;

  const int gb = (N + 127) / 128;
  const int NB = (N + 1023) / 1024;

  k_cvt_w<<<(NT * HD * HD + 6 * HD * HD + 255) / 256, 256, 0, stream>>>(
      W_edge, (const float*)d_in[3], (const float*)d_in[5], (const float*)d_in[7],
      (const float*)d_in[9], (const float*)d_in[10], (const float*)d_in[11], WeT, WgT);

  if (ws_size >= csr_need) {
    // ---- CSR gather path ----
    hipMemsetAsync(deg, 0, (size_t)N * 4, stream);
    k_gemm_edge<<<dim3(gb, NT), 256, 0, stream>>>(X, WeT, b_edge, P, N, NT * HD, -1);
    k_count<<<1024, 256, 0, stream>>>(dst, nePtr, deg);
    k_scan_a<<<NB, 256, 0, stream>>>(deg, offA, bsum, N);
    k_scan_b<<<1, 1024, 0, stream>>>(bsum, NB);
    k_scan_c<<<NB, 256, 0, stream>>>(offA, bsum, N);
    k_fill<<<1024, 256, 0, stream>>>(src, dst, typ, nePtr, offA, elist);
    k_gather_gru<<<(N + 63) / 64, 256, 0, stream>>>(
        X, P, deg, offA, elist, WgT, b_ir, b_iz, b_in, b_hn, (float*)d_out, N);
  } else {
    // ---- fallback: atomic scatter into d_out, standalone GRU ----
    float* agg = (float*)d_out;
    hipMemsetAsync(d_out, 0, (size_t)out_size * sizeof(float), stream);
    size_t pneed = base_need + (size_t)N * NT * HD * 2;
    if (ws_size >= pneed) {
      u16* Pf = (u16*)(ws + base_need);
      k_gemm_edge<<<dim3(gb, NT), 256, 0, stream>>>(X, WeT, b_edge, Pf, N, NT * HD, -1);
      k_scatter<<<2048, 256, 0, stream>>>(Pf, src, dst, typ, nePtr, agg, NT * HD, -1);
      k_gru<<<(N + 63) / 64, 256, 0, stream>>>(X, agg, WgT, b_ir, b_iz, b_in, b_hn, agg, N);
    } else {
      u16* Pt = (u16*)(ws + base_need);
      for (int t = 0; t < NT; ++t) {
        k_gemm_edge<<<dim3(gb, 1), 256, 0, stream>>>(X, WeT, b_edge, Pt, N, HD, t);
        k_scatter<<<2048, 256, 0, stream>>>(Pt, src, dst, typ, nePtr, agg, HD, t);
      }
      k_gru<<<(N + 63) / 64, 256, 0, stream>>>(X, agg, WgT, b_ir, b_iz, b_in, b_hn, agg, N);
    }
  }
}

// Round 4
// 371.169 us; speedup vs baseline: 3.8554x; 1.6926x over previous
//
#include <hip/hip_runtime.h>
#include <hip/hip_bf16.h>

#define HD 128
#define NT 6

typedef unsigned short u16;
typedef unsigned int u32;
typedef __attribute__((ext_vector_type(8))) short bf16x8;
typedef __attribute__((ext_vector_type(4))) float f32x4;

__device__ __forceinline__ float sigmoidf_(float x) {
  return 1.0f / (1.0f + __expf(-x));
}

// f32 -> bf16 (RNE)
__device__ __forceinline__ u16 f2bf(float x) {
  u32 u = __float_as_uint(x);
  return (u16)((u + 0x7FFFu + ((u >> 16) & 1u)) >> 16);
}
__device__ __forceinline__ float bflo(u32 v) { return __uint_as_float(v << 16); }
__device__ __forceinline__ float bfhi(u32 v) { return __uint_as_float(v & 0xffff0000u); }

// XOR swizzle for 256B-row bf16 LDS tiles (involution, both sides).
__device__ __forceinline__ int swz(int p) { return p ^ (((p >> 8) & 7) << 4); }

// ============ weight convert+transpose: W^T bf16 ============
__global__ void k_cvt_w(const float* __restrict__ We,
                        const float* __restrict__ Wir, const float* __restrict__ Wiz,
                        const float* __restrict__ Win, const float* __restrict__ Whr,
                        const float* __restrict__ Whz, const float* __restrict__ Whn,
                        u16* __restrict__ WeT, u16* __restrict__ WgT) {
  int i = blockIdx.x * blockDim.x + threadIdx.x;
  if (i < NT * HD * HD) {
    int c = i >> 7, k = i & 127;                 // WeT[c][k] = We[k][c]
    WeT[i] = f2bf(We[(size_t)k * (NT * HD) + c]);
  } else {
    int j = i - NT * HD * HD;
    if (j < 6 * HD * HD) {
      int m = j >> 14, jj = j & 16383;
      int c = jj >> 7, k = jj & 127;
      const float* W = (m == 0) ? Wir : (m == 1) ? Wiz : (m == 2) ? Win
                     : (m == 3) ? Whr : (m == 4) ? Whz : Whn;
      WgT[j] = f2bf(W[(size_t)k * HD + c]);
    }
  }
}

// ============ Edge projection GEMM, all 6 types per block ============
// Stages X tile once; restages 32KB W tile per type. P[row][t*128+col].
__global__ __launch_bounds__(256) void k_gemm_edge6(
    const float* __restrict__ X, const u16* __restrict__ WeT,
    const float* __restrict__ Be, u16* __restrict__ P, int N)
{
  __shared__ char As[32768];   // 128 rows x 128 k bf16 (swizzled)
  __shared__ char Bs[32768];
  const int tid = threadIdx.x;
  const int row0 = blockIdx.x * 128;

  #pragma unroll
  for (int i = 0; i < 8; ++i) {
    int p = i * 4096 + tid * 16;
    int row = row0 + (p >> 8);
    union { u16 u[8]; bf16x8 v; } ra;
    if (row < N) {
      const float4* s = (const float4*)(X + (size_t)row0 * HD + (p >> 1));
      float4 f0 = s[0], f1 = s[1];
      ra.u[0] = f2bf(f0.x); ra.u[1] = f2bf(f0.y); ra.u[2] = f2bf(f0.z); ra.u[3] = f2bf(f0.w);
      ra.u[4] = f2bf(f1.x); ra.u[5] = f2bf(f1.y); ra.u[6] = f2bf(f1.z); ra.u[7] = f2bf(f1.w);
    } else {
      #pragma unroll
      for (int j = 0; j < 8; ++j) ra.u[j] = 0;
    }
    *(bf16x8*)(As + swz(p)) = ra.v;
  }

  const int l = tid & 63, w = tid >> 6;
  const int m0 = (w >> 1) * 64, n0 = (w & 1) * 64;
  const int lr = l & 15, lg = l >> 4;
  f32x4 zero = {0.f, 0.f, 0.f, 0.f};

  for (int t = 0; t < NT; ++t) {
    __syncthreads();             // As ready (t=0) / prev Bs reads done (t>0)
    const char* gB = (const char*)(WeT + (size_t)t * HD * HD);
    #pragma unroll
    for (int i = 0; i < 8; ++i) {
      int p = i * 4096 + tid * 16;
      *(bf16x8*)(Bs + swz(p)) = *(const bf16x8*)(gB + p);
    }
    __syncthreads();

    f32x4 acc[4][4];
    #pragma unroll
    for (int m = 0; m < 4; ++m)
      #pragma unroll
      for (int n = 0; n < 4; ++n) acc[m][n] = zero;

    #pragma unroll
    for (int k = 0; k < 4; ++k) {
      bf16x8 a[4], b[4];
      #pragma unroll
      for (int m = 0; m < 4; ++m)
        a[m] = *(const bf16x8*)(As + swz((m0 + m * 16 + lr) * 256 + k * 64 + lg * 16));
      #pragma unroll
      for (int n = 0; n < 4; ++n)
        b[n] = *(const bf16x8*)(Bs + swz((n0 + n * 16 + lr) * 256 + k * 64 + lg * 16));
      #pragma unroll
      for (int m = 0; m < 4; ++m)
        #pragma unroll
        for (int n = 0; n < 4; ++n)
          acc[m][n] = __builtin_amdgcn_mfma_f32_16x16x32_bf16(a[m], b[n], acc[m][n], 0, 0, 0);
    }

    float bias[4];
    #pragma unroll
    for (int n = 0; n < 4; ++n) bias[n] = Be[t * HD + n0 + n * 16 + lr];
    #pragma unroll
    for (int m = 0; m < 4; ++m) {
      int rbase = row0 + m0 + m * 16 + lg * 4;
      #pragma unroll
      for (int j = 0; j < 4; ++j) {
        int row = rbase + j;
        if (row < N) {
          #pragma unroll
          for (int n = 0; n < 4; ++n)
            P[(size_t)row * (NT * HD) + t * HD + n0 + n * 16 + lr] =
                f2bf(acc[m][n][j] + bias[n]);
        }
      }
    }
  }
}

// ============ CSR build ============
__global__ __launch_bounds__(256) void k_count(const int* __restrict__ dst,
                                               const int* __restrict__ nePtr,
                                               int* __restrict__ deg) {
  const int ne = nePtr[0];
  for (int e = blockIdx.x * blockDim.x + threadIdx.x; e < ne;
       e += gridDim.x * blockDim.x)
    atomicAdd(&deg[dst[e]], 1);
}

__global__ __launch_bounds__(256) void k_scan_a(const int* __restrict__ deg,
                                                int* __restrict__ off,
                                                int* __restrict__ bsum, int N) {
  __shared__ int s[256];
  const int b = blockIdx.x, tid = threadIdx.x;
  const int base = b * 1024 + tid * 4;
  int v0 = 0, v1 = 0, v2 = 0, v3 = 0;
  if (base < N) v0 = deg[base];
  if (base + 1 < N) v1 = deg[base + 1];
  if (base + 2 < N) v2 = deg[base + 2];
  if (base + 3 < N) v3 = deg[base + 3];
  const int sum = v0 + v1 + v2 + v3;
  s[tid] = sum;
  __syncthreads();
  for (int d = 1; d < 256; d <<= 1) {
    int t = (tid >= d) ? s[tid - d] : 0;
    __syncthreads();
    s[tid] += t;
    __syncthreads();
  }
  const int excl = s[tid] - sum;
  if (base < N) off[base] = excl;
  if (base + 1 < N) off[base + 1] = excl + v0;
  if (base + 2 < N) off[base + 2] = excl + v0 + v1;
  if (base + 3 < N) off[base + 3] = excl + v0 + v1 + v2;
  if (tid == 255) bsum[b] = s[255];
}

__global__ void k_scan_b(int* __restrict__ bsum, int nb) {
  __shared__ int s[1024];
  const int tid = threadIdx.x;
  const int v = (tid < nb) ? bsum[tid] : 0;
  s[tid] = v;
  __syncthreads();
  for (int d = 1; d < 1024; d <<= 1) {
    int t = (tid >= d) ? s[tid - d] : 0;
    __syncthreads();
    s[tid] += t;
    __syncthreads();
  }
  if (tid < nb) bsum[tid] = s[tid] - v;   // exclusive
}

__global__ __launch_bounds__(256) void k_scan_c(int* __restrict__ off,
                                                const int* __restrict__ bsum, int N) {
  const int b = blockIdx.x, tid = threadIdx.x;
  const int add = bsum[b];
  const int base = b * 1024 + tid * 4;
  #pragma unroll
  for (int i = 0; i < 4; ++i)
    if (base + i < N) off[base + i] += add;
}

__global__ __launch_bounds__(256) void k_fill(const int* __restrict__ src,
                                              const int* __restrict__ dst,
                                              const int* __restrict__ typ,
                                              const int* __restrict__ nePtr,
                                              int* __restrict__ off,
                                              u32* __restrict__ elist) {
  const int ne = nePtr[0];
  for (int e = blockIdx.x * blockDim.x + threadIdx.x; e < ne;
       e += gridDim.x * blockDim.x) {
    int pos = atomicAdd(&off[dst[e]], 1);
    elist[pos] = (u32)(src[e] * NT + typ[e]);   // P-row index
  }
}

// ============ Standalone gather: one wave per node, 4-deep MLP ============
__global__ __launch_bounds__(256) void k_gather(
    const u16* __restrict__ P, const int* __restrict__ deg,
    const int* __restrict__ off, const u32* __restrict__ elist,
    u16* __restrict__ Hb, int N)
{
  const int l = threadIdx.x & 63;
  int wid = (int)((blockIdx.x * blockDim.x + threadIdx.x) >> 6);
  int nw = (int)((gridDim.x * blockDim.x) >> 6);
  for (int n = wid; n < N; n += nw) {
    const int e1 = off[n];
    const int e0 = e1 - deg[n];
    float a0 = 0.f, a1 = 0.f, b0 = 0.f, b1 = 0.f;
    int e = e0;
    for (; e + 4 <= e1; e += 4) {
      u32 p0 = elist[e], p1 = elist[e + 1], p2 = elist[e + 2], p3 = elist[e + 3];
      u32 v0 = *((const u32*)(P + (size_t)p0 * HD) + l);
      u32 v1 = *((const u32*)(P + (size_t)p1 * HD) + l);
      u32 v2 = *((const u32*)(P + (size_t)p2 * HD) + l);
      u32 v3 = *((const u32*)(P + (size_t)p3 * HD) + l);
      a0 += bflo(v0); a1 += bfhi(v0);
      b0 += bflo(v1); b1 += bfhi(v1);
      a0 += bflo(v2); a1 += bfhi(v2);
      b0 += bflo(v3); b1 += bfhi(v3);
    }
    for (; e < e1; ++e) {
      u32 v = *((const u32*)(P + (size_t)elist[e] * HD) + l);
      a0 += bflo(v); a1 += bfhi(v);
    }
    a0 += b0; a1 += b1;
    u32 hp = ((u32)f2bf(a1) << 16) | (u32)f2bf(a0);
    *((u32*)(Hb + (size_t)n * HD) + l) = hp;
  }
}

// ============ GRU from bf16 h (MFMA, barrier-free per wave) ============
__global__ __launch_bounds__(256) void k_gru_bf(
    const float* __restrict__ X, const u16* __restrict__ Hb,
    const u16* __restrict__ WgT,
    const float* __restrict__ bir, const float* __restrict__ biz,
    const float* __restrict__ bin_, const float* __restrict__ bhn,
    float* __restrict__ out, int N)
{
  __shared__ char Xs[16384];   // 64 rows x 128 k bf16 (swizzled)
  __shared__ char Hs[16384];
  const int tid = threadIdx.x;
  const int row0 = blockIdx.x * 64;

  #pragma unroll
  for (int i = 0; i < 4; ++i) {
    int p = i * 4096 + tid * 16;
    int row = row0 + (p >> 8);
    union { u16 u[8]; bf16x8 v; } rx, rh;
    if (row < N) {
      const float4* sx = (const float4*)(X + (size_t)row0 * HD + (p >> 1));
      float4 x0 = sx[0], x1 = sx[1];
      rx.u[0] = f2bf(x0.x); rx.u[1] = f2bf(x0.y); rx.u[2] = f2bf(x0.z); rx.u[3] = f2bf(x0.w);
      rx.u[4] = f2bf(x1.x); rx.u[5] = f2bf(x1.y); rx.u[6] = f2bf(x1.z); rx.u[7] = f2bf(x1.w);
      rh.v = *(const bf16x8*)((const char*)Hb + (size_t)row0 * 256 + p);
    } else {
      #pragma unroll
      for (int j = 0; j < 8; ++j) { rx.u[j] = 0; rh.u[j] = 0; }
    }
    *(bf16x8*)(Xs + swz(p)) = rx.v;
    *(bf16x8*)(Hs + swz(p)) = rh.v;
  }
  __syncthreads();

  const int l = tid & 63, w = tid >> 6;
  const int lr = l & 15, lg = l >> 4;
  const int rloc = w * 16;

  f32x4 zero = {0.f, 0.f, 0.f, 0.f};
  auto sweep = [&](const char* Ab, const u16* WT, f32x4* acc) {
    #pragma unroll
    for (int n = 0; n < 8; ++n) acc[n] = zero;
    #pragma unroll
    for (int k = 0; k < 4; ++k) {
      bf16x8 a = *(const bf16x8*)(Ab + swz((rloc + lr) * 256 + k * 64 + lg * 16));
      #pragma unroll
      for (int n = 0; n < 8; ++n) {
        bf16x8 b = *(const bf16x8*)(WT + (size_t)(n * 16 + lr) * HD + k * 32 + lg * 8);
        acc[n] = __builtin_amdgcn_mfma_f32_16x16x32_bf16(a, b, acc[n], 0, 0, 0);
      }
    }
  };

  f32x4 t1[8], t2[8], rg[8], nn[8];
  float bv[8];

  sweep(Xs, WgT + 0 * HD * HD, t1);            // xWir
  sweep(Hs, WgT + 3 * HD * HD, t2);            // hWhr
  #pragma unroll
  for (int n = 0; n < 8; ++n) bv[n] = bir[n * 16 + lr];
  #pragma unroll
  for (int n = 0; n < 8; ++n)
    #pragma unroll
    for (int j = 0; j < 4; ++j) rg[n][j] = sigmoidf_(t1[n][j] + bv[n] + t2[n][j]);

  sweep(Hs, WgT + 5 * HD * HD, t2);            // hWhn
  #pragma unroll
  for (int n = 0; n < 8; ++n) bv[n] = bhn[n * 16 + lr];
  #pragma unroll
  for (int n = 0; n < 8; ++n)
    #pragma unroll
    for (int j = 0; j < 4; ++j) rg[n][j] *= (t2[n][j] + bv[n]);

  sweep(Xs, WgT + 2 * HD * HD, t1);            // xWin
  #pragma unroll
  for (int n = 0; n < 8; ++n) bv[n] = bin_[n * 16 + lr];
  #pragma unroll
  for (int n = 0; n < 8; ++n)
    #pragma unroll
    for (int j = 0; j < 4; ++j) nn[n][j] = tanhf(t1[n][j] + bv[n] + rg[n][j]);

  sweep(Xs, WgT + 1 * HD * HD, t1);            // xWiz
  sweep(Hs, WgT + 4 * HD * HD, t2);            // hWhz
  #pragma unroll
  for (int n = 0; n < 8; ++n) bv[n] = biz[n * 16 + lr];
  #pragma unroll
  for (int n = 0; n < 8; ++n) {
    #pragma unroll
    for (int j = 0; j < 4; ++j) {
      int row = row0 + rloc + lg * 4 + j;
      if (row < N) {
        float z = sigmoidf_(t1[n][j] + bv[n] + t2[n][j]);
        u16 hu = *(const u16*)(Hs + swz((rloc + lg * 4 + j) * 256 + (n * 16 + lr) * 2));
        float h = __uint_as_float((u32)hu << 16);
        out[(size_t)row * HD + n * 16 + lr] = (1.0f - z) * nn[n][j] + z * h;
      }
    }
  }
}

// ============ Fused gather+GRU (mid-tier fallback, 4-deep unroll) ============
__global__ __launch_bounds__(256) void k_gather_gru(
    const float* __restrict__ X, const u16* __restrict__ P,
    const int* __restrict__ deg, const int* __restrict__ off,
    const u32* __restrict__ elist, const u16* __restrict__ WgT,
    const float* __restrict__ bir, const float* __restrict__ biz,
    const float* __restrict__ bin_, const float* __restrict__ bhn,
    float* __restrict__ out, int N)
{
  __shared__ char Xs[16384];
  __shared__ char Hs[16384];
  const int tid = threadIdx.x;
  const int l = tid & 63, w = tid >> 6;
  const int row0 = blockIdx.x * 64;
  const int wr0 = w * 16;

  #pragma unroll
  for (int it = 0; it < 4; ++it) {
    int chunk = it * 64 + l;
    int r = chunk >> 4, seg = chunk & 15;
    int grow = row0 + wr0 + r;
    union { u16 u[8]; bf16x8 v; } rx;
    if (grow < N) {
      const float4* sx = (const float4*)(X + (size_t)grow * HD + seg * 8);
      float4 x0 = sx[0], x1 = sx[1];
      rx.u[0] = f2bf(x0.x); rx.u[1] = f2bf(x0.y); rx.u[2] = f2bf(x0.z); rx.u[3] = f2bf(x0.w);
      rx.u[4] = f2bf(x1.x); rx.u[5] = f2bf(x1.y); rx.u[6] = f2bf(x1.z); rx.u[7] = f2bf(x1.w);
    } else {
      #pragma unroll
      for (int j = 0; j < 8; ++j) rx.u[j] = 0;
    }
    *(bf16x8*)(Xs + swz((wr0 + r) * 256 + seg * 16)) = rx.v;
  }

  for (int i = 0; i < 16; ++i) {
    int n = row0 + wr0 + i;
    float a0 = 0.f, a1 = 0.f, b0 = 0.f, b1 = 0.f;
    if (n < N) {
      int e1 = off[n];
      int e = e1 - deg[n];
      for (; e + 4 <= e1; e += 4) {
        u32 p0 = elist[e], p1 = elist[e + 1], p2 = elist[e + 2], p3 = elist[e + 3];
        u32 v0 = *((const u32*)(P + (size_t)p0 * HD) + l);
        u32 v1 = *((const u32*)(P + (size_t)p1 * HD) + l);
        u32 v2 = *((const u32*)(P + (size_t)p2 * HD) + l);
        u32 v3 = *((const u32*)(P + (size_t)p3 * HD) + l);
        a0 += bflo(v0); a1 += bfhi(v0);
        b0 += bflo(v1); b1 += bfhi(v1);
        a0 += bflo(v2); a1 += bfhi(v2);
        b0 += bflo(v3); b1 += bfhi(v3);
      }
      for (; e < e1; ++e) {
        u32 v = *((const u32*)(P + (size_t)elist[e] * HD) + l);
        a0 += bflo(v); a1 += bfhi(v);
      }
    }
    a0 += b0; a1 += b1;
    u32 hp = ((u32)f2bf(a1) << 16) | (u32)f2bf(a0);
    *(u32*)(Hs + swz((wr0 + i) * 256 + l * 4)) = hp;
  }

  const int lr = l & 15, lg = l >> 4;
  const int rloc = wr0;

  f32x4 zero = {0.f, 0.f, 0.f, 0.f};
  auto sweep = [&](const char* Ab, const u16* WT, f32x4* acc) {
    #pragma unroll
    for (int n = 0; n < 8; ++n) acc[n] = zero;
    #pragma unroll
    for (int k = 0; k < 4; ++k) {
      bf16x8 a = *(const bf16x8*)(Ab + swz((rloc + lr) * 256 + k * 64 + lg * 16));
      #pragma unroll
      for (int n = 0; n < 8; ++n) {
        bf16x8 b = *(const bf16x8*)(WT + (size_t)(n * 16 + lr) * HD + k * 32 + lg * 8);
        acc[n] = __builtin_amdgcn_mfma_f32_16x16x32_bf16(a, b, acc[n], 0, 0, 0);
      }
    }
  };

  f32x4 t1[8], t2[8], rg[8], nn[8];
  float bv[8];

  sweep(Xs, WgT + 0 * HD * HD, t1);
  sweep(Hs, WgT + 3 * HD * HD, t2);
  #pragma unroll
  for (int n = 0; n < 8; ++n) bv[n] = bir[n * 16 + lr];
  #pragma unroll
  for (int n = 0; n < 8; ++n)
    #pragma unroll
    for (int j = 0; j < 4; ++j) rg[n][j] = sigmoidf_(t1[n][j] + bv[n] + t2[n][j]);

  sweep(Hs, WgT + 5 * HD * HD, t2);
  #pragma unroll
  for (int n = 0; n < 8; ++n) bv[n] = bhn[n * 16 + lr];
  #pragma unroll
  for (int n = 0; n < 8; ++n)
    #pragma unroll
    for (int j = 0; j < 4; ++j) rg[n][j] *= (t2[n][j] + bv[n]);

  sweep(Xs, WgT + 2 * HD * HD, t1);
  #pragma unroll
  for (int n = 0; n < 8; ++n) bv[n] = bin_[n * 16 + lr];
  #pragma unroll
  for (int n = 0; n < 8; ++n)
    #pragma unroll
    for (int j = 0; j < 4; ++j) nn[n][j] = tanhf(t1[n][j] + bv[n] + rg[n][j]);

  sweep(Xs, WgT + 1 * HD * HD, t1);
  sweep(Hs, WgT + 4 * HD * HD, t2);
  #pragma unroll
  for (int n = 0; n < 8; ++n) bv[n] = biz[n * 16 + lr];
  #pragma unroll
  for (int n = 0; n < 8; ++n) {
    #pragma unroll
    for (int j = 0; j < 4; ++j) {
      int row = row0 + rloc + lg * 4 + j;
      if (row < N) {
        float z = sigmoidf_(t1[n][j] + bv[n] + t2[n][j]);
        u16 hu = *(const u16*)(Hs + swz((rloc + lg * 4 + j) * 256 + (n * 16 + lr) * 2));
        float h = __uint_as_float((u32)hu << 16);
        out[(size_t)row * HD + n * 16 + lr] = (1.0f - z) * nn[n][j] + z * h;
      }
    }
  }
}

// ============ Lowest-tier fallback: atomic scatter + f32-agg GRU ============
__global__ __launch_bounds__(256) void k_scatter(
    const u16* __restrict__ P, const int* __restrict__ src,
    const int* __restrict__ dst, const int* __restrict__ typ,
    const int* __restrict__ nePtr, float* __restrict__ agg,
    int ldP, int fixedType)
{
  const int ne = nePtr[0];
  const int lane = threadIdx.x & 63;
  const int wid = (int)((blockIdx.x * blockDim.x + threadIdx.x) >> 6);
  const int nw = (int)((gridDim.x * blockDim.x) >> 6);
  for (int e = wid; e < ne; e += nw) {
    const int t = typ[e];
    if (fixedType >= 0 && t != fixedType) continue;
    const size_t po = (ldP == HD) ? (size_t)src[e] * HD
                                  : (size_t)src[e] * (NT * HD) + (size_t)t * HD;
    u32 v = *(const u32*)(P + po + lane * 2);
    float* o = agg + (size_t)dst[e] * HD + lane * 2;
    unsafeAtomicAdd(o, bflo(v));
    unsafeAtomicAdd(o + 1, bfhi(v));
  }
}

__global__ __launch_bounds__(256) void k_gru(
    const float* __restrict__ X, const float* __restrict__ agg,
    const u16* __restrict__ WgT,
    const float* __restrict__ bir, const float* __restrict__ biz,
    const float* __restrict__ bin_, const float* __restrict__ bhn,
    float* __restrict__ out, int N)
{
  __shared__ char Xs[16384];
  __shared__ char Hs[16384];
  const int tid = threadIdx.x;
  const int row0 = blockIdx.x * 64;

  #pragma unroll
  for (int i = 0; i < 4; ++i) {
    int p = i * 4096 + tid * 16;
    int row = row0 + (p >> 8);
    union { u16 u[8]; bf16x8 v; } rx, rh;
    if (row < N) {
      const float4* sx = (const float4*)(X + (size_t)row0 * HD + (p >> 1));
      const float4* sh = (const float4*)(agg + (size_t)row0 * HD + (p >> 1));
      float4 x0 = sx[0], x1 = sx[1], h0 = sh[0], h1 = sh[1];
      rx.u[0] = f2bf(x0.x); rx.u[1] = f2bf(x0.y); rx.u[2] = f2bf(x0.z); rx.u[3] = f2bf(x0.w);
      rx.u[4] = f2bf(x1.x); rx.u[5] = f2bf(x1.y); rx.u[6] = f2bf(x1.z); rx.u[7] = f2bf(x1.w);
      rh.u[0] = f2bf(h0.x); rh.u[1] = f2bf(h0.y); rh.u[2] = f2bf(h0.z); rh.u[3] = f2bf(h0.w);
      rh.u[4] = f2bf(h1.x); rh.u[5] = f2bf(h1.y); rh.u[6] = f2bf(h1.z); rh.u[7] = f2bf(h1.w);
    } else {
      #pragma unroll
      for (int j = 0; j < 8; ++j) { rx.u[j] = 0; rh.u[j] = 0; }
    }
    *(bf16x8*)(Xs + swz(p)) = rx.v;
    *(bf16x8*)(Hs + swz(p)) = rh.v;
  }
  __syncthreads();

  const int l = tid & 63, w = tid >> 6;
  const int lr = l & 15, lg = l >> 4;
  const int rloc = w * 16;

  f32x4 zero = {0.f, 0.f, 0.f, 0.f};
  auto sweep = [&](const char* Ab, const u16* WT, f32x4* acc) {
    #pragma unroll
    for (int n = 0; n < 8; ++n) acc[n] = zero;
    #pragma unroll
    for (int k = 0; k < 4; ++k) {
      bf16x8 a = *(const bf16x8*)(Ab + swz((rloc + lr) * 256 + k * 64 + lg * 16));
      #pragma unroll
      for (int n = 0; n < 8; ++n) {
        bf16x8 b = *(const bf16x8*)(WT + (size_t)(n * 16 + lr) * HD + k * 32 + lg * 8);
        acc[n] = __builtin_amdgcn_mfma_f32_16x16x32_bf16(a, b, acc[n], 0, 0, 0);
      }
    }
  };

  f32x4 t1[8], t2[8], rg[8], nn[8];
  float bv[8];

  sweep(Xs, WgT + 0 * HD * HD, t1);
  sweep(Hs, WgT + 3 * HD * HD, t2);
  #pragma unroll
  for (int n = 0; n < 8; ++n) bv[n] = bir[n * 16 + lr];
  #pragma unroll
  for (int n = 0; n < 8; ++n)
    #pragma unroll
    for (int j = 0; j < 4; ++j) rg[n][j] = sigmoidf_(t1[n][j] + bv[n] + t2[n][j]);

  sweep(Hs, WgT + 5 * HD * HD, t2);
  #pragma unroll
  for (int n = 0; n < 8; ++n) bv[n] = bhn[n * 16 + lr];
  #pragma unroll
  for (int n = 0; n < 8; ++n)
    #pragma unroll
    for (int j = 0; j < 4; ++j) rg[n][j] *= (t2[n][j] + bv[n]);

  sweep(Xs, WgT + 2 * HD * HD, t1);
  #pragma unroll
  for (int n = 0; n < 8; ++n) bv[n] = bin_[n * 16 + lr];
  #pragma unroll
  for (int n = 0; n < 8; ++n)
    #pragma unroll
    for (int j = 0; j < 4; ++j) nn[n][j] = tanhf(t1[n][j] + bv[n] + rg[n][j]);

  sweep(Xs, WgT + 1 * HD * HD, t1);
  sweep(Hs, WgT + 4 * HD * HD, t2);
  #pragma unroll
  for (int n = 0; n < 8; ++n) bv[n] = biz[n * 16 + lr];
  #pragma unroll
  for (int n = 0; n < 8; ++n) {
    #pragma unroll
    for (int j = 0; j < 4; ++j) {
      int row = row0 + rloc + lg * 4 + j;
      if (row < N) {
        float z = sigmoidf_(t1[n][j] + bv[n] + t2[n][j]);
        float h = agg[(size_t)row * HD + n * 16 + lr];
        out[(size_t)row * HD + n * 16 + lr] = (1.0f - z) * nn[n][j] + z * h;
      }
    }
  }
}

extern "C" void kernel_launch(void* const* d_in, const int* in_sizes, int n_in,
                              void* d_out, int out_size, void* d_ws, size_t ws_size,
                              hipStream_t stream) {
  const float* X      = (const float*)d_in[0];
  const float* W_edge = (const float*)d_in[1];
  const float* b_edge = (const float*)d_in[2];
  const float* b_ir   = (const float*)d_in[4];
  const float* b_iz   = (const float*)d_in[6];
  const float* b_in   = (const float*)d_in[8];
  const float* b_hn   = (const float*)d_in[12];
  const int* src      = (const int*)d_in[13];
  const int* dst      = (const int*)d_in[14];
  const int* typ      = (const int*)d_in[15];
  const int* nePtr    = (const int*)d_in[16];

  const int N = in_sizes[0] / HD;
  const int E = in_sizes[13];
  char* ws = (char*)d_ws;

  size_t cur = 0;
  auto alloc = [&](size_t bytes) {
    size_t p = cur;
    cur = (cur + bytes + 255) & ~(size_t)255;
    return p;
  };
  u16* WeT   = (u16*)(ws + alloc((size_t)NT * HD * HD * 2));
  u16* WgT   = (u16*)(ws + alloc((size_t)6 * HD * HD * 2));
  int* deg   = (int*)(ws + alloc((size_t)N * 4));
  int* offA  = (int*)(ws + alloc((size_t)N * 4));
  int* bsum  = (int*)(ws + alloc(1024 * 4));
  u32* elist = (u32*)(ws + alloc((size_t)E * 4));
  size_t base_need = cur;
  u16* P     = (u16*)(ws + alloc((size_t)N * NT * HD * 2));
  const size_t csr_need = cur;
  u16* Hb    = (u16*)(ws + alloc((size_t)N * HD * 2));
  const size_t split_need = cur;

  const int gb = (N + 127) / 128;
  const int NB = (N + 1023) / 1024;

  k_cvt_w<<<(NT * HD * HD + 6 * HD * HD + 255) / 256, 256, 0, stream>>>(
      W_edge, (const float*)d_in[3], (const float*)d_in[5], (const float*)d_in[7],
      (const float*)d_in[9], (const float*)d_in[10], (const float*)d_in[11], WeT, WgT);

  if (ws_size >= csr_need) {
    hipMemsetAsync(deg, 0, (size_t)N * 4, stream);
    k_gemm_edge6<<<gb, 256, 0, stream>>>(X, WeT, b_edge, P, N);
    k_count<<<1024, 256, 0, stream>>>(dst, nePtr, deg);
    k_scan_a<<<NB, 256, 0, stream>>>(deg, offA, bsum, N);
    k_scan_b<<<1, 1024, 0, stream>>>(bsum, NB);
    k_scan_c<<<NB, 256, 0, stream>>>(offA, bsum, N);
    k_fill<<<1024, 256, 0, stream>>>(src, dst, typ, nePtr, offA, elist);
    if (ws_size >= split_need) {
      // ---- split path: high-MLP gather, then GRU ----
      k_gather<<<(N + 3) / 4, 256, 0, stream>>>(P, deg, offA, elist, Hb, N);
      k_gru_bf<<<(N + 63) / 64, 256, 0, stream>>>(
          X, Hb, WgT, b_ir, b_iz, b_in, b_hn, (float*)d_out, N);
    } else {
      k_gather_gru<<<(N + 63) / 64, 256, 0, stream>>>(
          X, P, deg, offA, elist, WgT, b_ir, b_iz, b_in, b_hn, (float*)d_out, N);
    }
  } else {
    // ---- atomic fallback ----
    float* agg = (float*)d_out;
    hipMemsetAsync(d_out, 0, (size_t)out_size * sizeof(float), stream);
    size_t pneed = base_need + (size_t)N * NT * HD * 2;
    if (ws_size >= pneed) {
      u16* Pf = (u16*)(ws + base_need);
      k_gemm_edge6<<<gb, 256, 0, stream>>>(X, WeT, b_edge, Pf, N);
      k_scatter<<<2048, 256, 0, stream>>>(Pf, src, dst, typ, nePtr, agg, NT * HD, -1);
      k_gru<<<(N + 63) / 64, 256, 0, stream>>>(X, agg, WgT, b_ir, b_iz, b_in, b_hn, agg, N);
    }
  }
}

// Round 5
// 274.999 us; speedup vs baseline: 5.2036x; 1.3497x over previous
//
#include <hip/hip_runtime.h>
#include <hip/hip_bf16.h>

#define HD 128
#define NT 6

typedef unsigned short u16;
typedef unsigned int u32;
typedef __attribute__((ext_vector_type(8))) short bf16x8;
typedef __attribute__((ext_vector_type(4))) float f32x4;

__device__ __forceinline__ float sigmoidf_(float x) {
  return 1.0f / (1.0f + __expf(-x));
}

// f32 -> bf16 (RNE)
__device__ __forceinline__ u16 f2bf(float x) {
  u32 u = __float_as_uint(x);
  return (u16)((u + 0x7FFFu + ((u >> 16) & 1u)) >> 16);
}
__device__ __forceinline__ float bflo(u32 v) { return __uint_as_float(v << 16); }
__device__ __forceinline__ float bfhi(u32 v) { return __uint_as_float(v & 0xffff0000u); }

// XOR swizzle for 256B-row bf16 LDS tiles (involution, both sides).
__device__ __forceinline__ int swz(int p) { return p ^ (((p >> 8) & 7) << 4); }

// ============ weight convert+transpose: W^T bf16 ============
__global__ void k_cvt_w(const float* __restrict__ We,
                        const float* __restrict__ Wir, const float* __restrict__ Wiz,
                        const float* __restrict__ Win, const float* __restrict__ Whr,
                        const float* __restrict__ Whz, const float* __restrict__ Whn,
                        u16* __restrict__ WeT, u16* __restrict__ WgT) {
  int i = blockIdx.x * blockDim.x + threadIdx.x;
  if (i < NT * HD * HD) {
    int c = i >> 7, k = i & 127;                 // WeT[c][k] = We[k][c]
    WeT[i] = f2bf(We[(size_t)k * (NT * HD) + c]);
  } else {
    int j = i - NT * HD * HD;
    if (j < 6 * HD * HD) {
      int m = j >> 14, jj = j & 16383;
      int c = jj >> 7, k = jj & 127;
      const float* W = (m == 0) ? Wir : (m == 1) ? Wiz : (m == 2) ? Win
                     : (m == 3) ? Whr : (m == 4) ? Whz : Whn;
      WgT[j] = f2bf(W[(size_t)k * HD + c]);
    }
  }
}

// ============ Edge projection GEMM, all 6 types per block ============
__global__ __launch_bounds__(256) void k_gemm_edge6(
    const float* __restrict__ X, const u16* __restrict__ WeT,
    const float* __restrict__ Be, u16* __restrict__ P, int N)
{
  __shared__ char As[32768];   // 128 rows x 128 k bf16 (swizzled)
  __shared__ char Bs[32768];
  const int tid = threadIdx.x;
  const int row0 = blockIdx.x * 128;

  #pragma unroll
  for (int i = 0; i < 8; ++i) {
    int p = i * 4096 + tid * 16;
    int row = row0 + (p >> 8);
    union { u16 u[8]; bf16x8 v; } ra;
    if (row < N) {
      const float4* s = (const float4*)(X + (size_t)row0 * HD + (p >> 1));
      float4 f0 = s[0], f1 = s[1];
      ra.u[0] = f2bf(f0.x); ra.u[1] = f2bf(f0.y); ra.u[2] = f2bf(f0.z); ra.u[3] = f2bf(f0.w);
      ra.u[4] = f2bf(f1.x); ra.u[5] = f2bf(f1.y); ra.u[6] = f2bf(f1.z); ra.u[7] = f2bf(f1.w);
    } else {
      #pragma unroll
      for (int j = 0; j < 8; ++j) ra.u[j] = 0;
    }
    *(bf16x8*)(As + swz(p)) = ra.v;
  }

  const int l = tid & 63, w = tid >> 6;
  const int m0 = (w >> 1) * 64, n0 = (w & 1) * 64;
  const int lr = l & 15, lg = l >> 4;
  f32x4 zero = {0.f, 0.f, 0.f, 0.f};

  for (int t = 0; t < NT; ++t) {
    __syncthreads();
    const char* gB = (const char*)(WeT + (size_t)t * HD * HD);
    #pragma unroll
    for (int i = 0; i < 8; ++i) {
      int p = i * 4096 + tid * 16;
      *(bf16x8*)(Bs + swz(p)) = *(const bf16x8*)(gB + p);
    }
    __syncthreads();

    f32x4 acc[4][4];
    #pragma unroll
    for (int m = 0; m < 4; ++m)
      #pragma unroll
      for (int n = 0; n < 4; ++n) acc[m][n] = zero;

    #pragma unroll
    for (int k = 0; k < 4; ++k) {
      bf16x8 a[4], b[4];
      #pragma unroll
      for (int m = 0; m < 4; ++m)
        a[m] = *(const bf16x8*)(As + swz((m0 + m * 16 + lr) * 256 + k * 64 + lg * 16));
      #pragma unroll
      for (int n = 0; n < 4; ++n)
        b[n] = *(const bf16x8*)(Bs + swz((n0 + n * 16 + lr) * 256 + k * 64 + lg * 16));
      #pragma unroll
      for (int m = 0; m < 4; ++m)
        #pragma unroll
        for (int n = 0; n < 4; ++n)
          acc[m][n] = __builtin_amdgcn_mfma_f32_16x16x32_bf16(a[m], b[n], acc[m][n], 0, 0, 0);
    }

    float bias[4];
    #pragma unroll
    for (int n = 0; n < 4; ++n) bias[n] = Be[t * HD + n0 + n * 16 + lr];
    #pragma unroll
    for (int m = 0; m < 4; ++m) {
      int rbase = row0 + m0 + m * 16 + lg * 4;
      #pragma unroll
      for (int j = 0; j < 4; ++j) {
        int row = rbase + j;
        if (row < N) {
          #pragma unroll
          for (int n = 0; n < 4; ++n)
            P[(size_t)row * (NT * HD) + t * HD + n0 + n * 16 + lr] =
                f2bf(acc[m][n][j] + bias[n]);
        }
      }
    }
  }
}

// ============ CSR build ============
__global__ __launch_bounds__(256) void k_count(const int* __restrict__ dst,
                                               const int* __restrict__ nePtr,
                                               int* __restrict__ deg) {
  const int ne = nePtr[0];
  for (int e = blockIdx.x * blockDim.x + threadIdx.x; e < ne;
       e += gridDim.x * blockDim.x)
    atomicAdd(&deg[dst[e]], 1);
}

__global__ __launch_bounds__(256) void k_scan_a(const int* __restrict__ deg,
                                                int* __restrict__ off,
                                                int* __restrict__ bsum, int N) {
  __shared__ int s[256];
  const int b = blockIdx.x, tid = threadIdx.x;
  const int base = b * 1024 + tid * 4;
  int v0 = 0, v1 = 0, v2 = 0, v3 = 0;
  if (base < N) v0 = deg[base];
  if (base + 1 < N) v1 = deg[base + 1];
  if (base + 2 < N) v2 = deg[base + 2];
  if (base + 3 < N) v3 = deg[base + 3];
  const int sum = v0 + v1 + v2 + v3;
  s[tid] = sum;
  __syncthreads();
  for (int d = 1; d < 256; d <<= 1) {
    int t = (tid >= d) ? s[tid - d] : 0;
    __syncthreads();
    s[tid] += t;
    __syncthreads();
  }
  const int excl = s[tid] - sum;
  if (base < N) off[base] = excl;
  if (base + 1 < N) off[base + 1] = excl + v0;
  if (base + 2 < N) off[base + 2] = excl + v0 + v1;
  if (base + 3 < N) off[base + 3] = excl + v0 + v1 + v2;
  if (tid == 255) bsum[b] = s[255];
}

__global__ void k_scan_b(int* __restrict__ bsum, int nb) {
  __shared__ int s[1024];
  const int tid = threadIdx.x;
  const int v = (tid < nb) ? bsum[tid] : 0;
  s[tid] = v;
  __syncthreads();
  for (int d = 1; d < 1024; d <<= 1) {
    int t = (tid >= d) ? s[tid - d] : 0;
    __syncthreads();
    s[tid] += t;
    __syncthreads();
  }
  if (tid < nb) bsum[tid] = s[tid] - v;   // exclusive
}

__global__ __launch_bounds__(256) void k_scan_c(int* __restrict__ off,
                                                const int* __restrict__ bsum, int N) {
  const int b = blockIdx.x, tid = threadIdx.x;
  const int add = bsum[b];
  const int base = b * 1024 + tid * 4;
  #pragma unroll
  for (int i = 0; i < 4; ++i)
    if (base + i < N) off[base + i] += add;
}

__global__ __launch_bounds__(256) void k_fill(const int* __restrict__ src,
                                              const int* __restrict__ dst,
                                              const int* __restrict__ typ,
                                              const int* __restrict__ nePtr,
                                              int* __restrict__ off,
                                              u32* __restrict__ elist) {
  const int ne = nePtr[0];
  for (int e = blockIdx.x * blockDim.x + threadIdx.x; e < ne;
       e += gridDim.x * blockDim.x) {
    int pos = atomicAdd(&off[dst[e]], 1);
    elist[pos] = (u32)(src[e] * NT + typ[e]);   // P-row index
  }
}

// ============ Standalone gather: one wave per node, masked 4-deep MLP ============
__global__ __launch_bounds__(256) void k_gather(
    const u16* __restrict__ P, const int* __restrict__ deg,
    const int* __restrict__ off, const u32* __restrict__ elist,
    u16* __restrict__ Hb, int N)
{
  const int l = threadIdx.x & 63;
  int wid = (int)((blockIdx.x * blockDim.x + threadIdx.x) >> 6);
  int nw = (int)((gridDim.x * blockDim.x) >> 6);
  for (int n = wid; n < N; n += nw) {
    const int e1 = off[n];
    const int e0 = e1 - deg[n];
    float a0 = 0.f, a1 = 0.f, b0 = 0.f, b1 = 0.f;
    for (int e = e0; e < e1; e += 4) {
      // masked 4-batch: OOB slots read a duplicate valid address, result masked
      u32 p0 = elist[e];
      u32 p1 = (e + 1 < e1) ? elist[e + 1] : p0;
      u32 p2 = (e + 2 < e1) ? elist[e + 2] : p0;
      u32 p3 = (e + 3 < e1) ? elist[e + 3] : p0;
      u32 v0 = *((const u32*)(P + (size_t)p0 * HD) + l);
      u32 v1 = *((const u32*)(P + (size_t)p1 * HD) + l);
      u32 v2 = *((const u32*)(P + (size_t)p2 * HD) + l);
      u32 v3 = *((const u32*)(P + (size_t)p3 * HD) + l);
      if (e + 1 >= e1) v1 = 0;
      if (e + 2 >= e1) v2 = 0;
      if (e + 3 >= e1) v3 = 0;
      a0 += bflo(v0); a1 += bfhi(v0);
      b0 += bflo(v1); b1 += bfhi(v1);
      a0 += bflo(v2); a1 += bfhi(v2);
      b0 += bflo(v3); b1 += bfhi(v3);
    }
    a0 += b0; a1 += b1;
    u32 hp = ((u32)f2bf(a1) << 16) | (u32)f2bf(a0);
    *((u32*)(Hb + (size_t)n * HD) + l) = hp;
  }
}

// ============ GRU v2: LDS-staged weights (bf16 MFMA) ============
__global__ __launch_bounds__(256) void k_gru2(
    const float* __restrict__ X, const u16* __restrict__ Hb,
    const u16* __restrict__ WgT,   // 6x[128][128] W^T: ir,iz,in,hr,hz,hn
    const float* __restrict__ bir, const float* __restrict__ biz,
    const float* __restrict__ bin_, const float* __restrict__ bhn,
    float* __restrict__ out, int N)
{
  __shared__ char Xs[16384];   // 64 rows x 128 k bf16 (swizzled)
  __shared__ char Hs[16384];
  __shared__ char Wb[32768];   // current gate's W^T, 128 cols x 128 k (swizzled)
  const int tid = threadIdx.x;
  const int row0 = blockIdx.x * 64;

  #pragma unroll
  for (int i = 0; i < 4; ++i) {
    int p = i * 4096 + tid * 16;
    int row = row0 + (p >> 8);
    union { u16 u[8]; bf16x8 v; } rx, rh;
    if (row < N) {
      const float4* sx = (const float4*)(X + (size_t)row0 * HD + (p >> 1));
      float4 x0 = sx[0], x1 = sx[1];
      rx.u[0] = f2bf(x0.x); rx.u[1] = f2bf(x0.y); rx.u[2] = f2bf(x0.z); rx.u[3] = f2bf(x0.w);
      rx.u[4] = f2bf(x1.x); rx.u[5] = f2bf(x1.y); rx.u[6] = f2bf(x1.z); rx.u[7] = f2bf(x1.w);
      rh.v = *(const bf16x8*)((const char*)Hb + (size_t)row0 * 256 + p);
    } else {
      #pragma unroll
      for (int j = 0; j < 8; ++j) { rx.u[j] = 0; rh.u[j] = 0; }
    }
    *(bf16x8*)(Xs + swz(p)) = rx.v;
    *(bf16x8*)(Hs + swz(p)) = rh.v;
  }

  const int l = tid & 63, w = tid >> 6;
  const int lr = l & 15, lg = l >> 4;
  const int rloc = w * 16;

  auto stageW = [&](const u16* WT) {
    const char* g = (const char*)WT;
    #pragma unroll
    for (int i = 0; i < 8; ++i) {
      int p = i * 4096 + tid * 16;
      *(bf16x8*)(Wb + swz(p)) = *(const bf16x8*)(g + p);
    }
  };

  f32x4 zero = {0.f, 0.f, 0.f, 0.f};
  auto sweepL = [&](const char* Ab, f32x4* acc) {
    #pragma unroll
    for (int n = 0; n < 8; ++n) acc[n] = zero;
    #pragma unroll
    for (int k = 0; k < 4; ++k) {
      bf16x8 a = *(const bf16x8*)(Ab + swz((rloc + lr) * 256 + k * 64 + lg * 16));
      #pragma unroll
      for (int n = 0; n < 8; ++n) {
        bf16x8 b = *(const bf16x8*)(Wb + swz((n * 16 + lr) * 256 + k * 64 + lg * 16));
        acc[n] = __builtin_amdgcn_mfma_f32_16x16x32_bf16(a, b, acc[n], 0, 0, 0);
      }
    }
  };

  f32x4 t1[8], t2[8], rg[8], nn[8];
  float bv[8];

  // r = sigmoid(xWir + bir + hWhr)
  __syncthreads(); stageW(WgT + 0 * HD * HD); __syncthreads();
  sweepL(Xs, t1);
  __syncthreads(); stageW(WgT + 3 * HD * HD); __syncthreads();
  sweepL(Hs, t2);
  #pragma unroll
  for (int n = 0; n < 8; ++n) bv[n] = bir[n * 16 + lr];
  #pragma unroll
  for (int n = 0; n < 8; ++n)
    #pragma unroll
    for (int j = 0; j < 4; ++j) rg[n][j] = sigmoidf_(t1[n][j] + bv[n] + t2[n][j]);

  // rn = r * (hWhn + bhn)
  __syncthreads(); stageW(WgT + 5 * HD * HD); __syncthreads();
  sweepL(Hs, t2);
  #pragma unroll
  for (int n = 0; n < 8; ++n) bv[n] = bhn[n * 16 + lr];
  #pragma unroll
  for (int n = 0; n < 8; ++n)
    #pragma unroll
    for (int j = 0; j < 4; ++j) rg[n][j] *= (t2[n][j] + bv[n]);

  // n = tanh(xWin + bin + rn)
  __syncthreads(); stageW(WgT + 2 * HD * HD); __syncthreads();
  sweepL(Xs, t1);
  #pragma unroll
  for (int n = 0; n < 8; ++n) bv[n] = bin_[n * 16 + lr];
  #pragma unroll
  for (int n = 0; n < 8; ++n)
    #pragma unroll
    for (int j = 0; j < 4; ++j) nn[n][j] = tanhf(t1[n][j] + bv[n] + rg[n][j]);

  // z = sigmoid(xWiz + biz + hWhz); out = (1-z)*n + z*h
  __syncthreads(); stageW(WgT + 1 * HD * HD); __syncthreads();
  sweepL(Xs, t1);
  __syncthreads(); stageW(WgT + 4 * HD * HD); __syncthreads();
  sweepL(Hs, t2);
  #pragma unroll
  for (int n = 0; n < 8; ++n) bv[n] = biz[n * 16 + lr];
  #pragma unroll
  for (int n = 0; n < 8; ++n) {
    #pragma unroll
    for (int j = 0; j < 4; ++j) {
      int row = row0 + rloc + lg * 4 + j;
      if (row < N) {
        float z = sigmoidf_(t1[n][j] + bv[n] + t2[n][j]);
        u16 hu = *(const u16*)(Hs + swz((rloc + lg * 4 + j) * 256 + (n * 16 + lr) * 2));
        float h = __uint_as_float((u32)hu << 16);
        out[(size_t)row * HD + n * 16 + lr] = (1.0f - z) * nn[n][j] + z * h;
      }
    }
  }
}

// ============ Fused gather+GRU (mid-tier fallback) ============
__global__ __launch_bounds__(256) void k_gather_gru(
    const float* __restrict__ X, const u16* __restrict__ P,
    const int* __restrict__ deg, const int* __restrict__ off,
    const u32* __restrict__ elist, const u16* __restrict__ WgT,
    const float* __restrict__ bir, const float* __restrict__ biz,
    const float* __restrict__ bin_, const float* __restrict__ bhn,
    float* __restrict__ out, int N)
{
  __shared__ char Xs[16384];
  __shared__ char Hs[16384];
  const int tid = threadIdx.x;
  const int l = tid & 63, w = tid >> 6;
  const int row0 = blockIdx.x * 64;
  const int wr0 = w * 16;

  #pragma unroll
  for (int it = 0; it < 4; ++it) {
    int chunk = it * 64 + l;
    int r = chunk >> 4, seg = chunk & 15;
    int grow = row0 + wr0 + r;
    union { u16 u[8]; bf16x8 v; } rx;
    if (grow < N) {
      const float4* sx = (const float4*)(X + (size_t)grow * HD + seg * 8);
      float4 x0 = sx[0], x1 = sx[1];
      rx.u[0] = f2bf(x0.x); rx.u[1] = f2bf(x0.y); rx.u[2] = f2bf(x0.z); rx.u[3] = f2bf(x0.w);
      rx.u[4] = f2bf(x1.x); rx.u[5] = f2bf(x1.y); rx.u[6] = f2bf(x1.z); rx.u[7] = f2bf(x1.w);
    } else {
      #pragma unroll
      for (int j = 0; j < 8; ++j) rx.u[j] = 0;
    }
    *(bf16x8*)(Xs + swz((wr0 + r) * 256 + seg * 16)) = rx.v;
  }

  for (int i = 0; i < 16; ++i) {
    int n = row0 + wr0 + i;
    float a0 = 0.f, a1 = 0.f;
    if (n < N) {
      int e1 = off[n];
      for (int e = e1 - deg[n]; e < e1; e += 4) {
        u32 p0 = elist[e];
        u32 p1 = (e + 1 < e1) ? elist[e + 1] : p0;
        u32 p2 = (e + 2 < e1) ? elist[e + 2] : p0;
        u32 p3 = (e + 3 < e1) ? elist[e + 3] : p0;
        u32 v0 = *((const u32*)(P + (size_t)p0 * HD) + l);
        u32 v1 = *((const u32*)(P + (size_t)p1 * HD) + l);
        u32 v2 = *((const u32*)(P + (size_t)p2 * HD) + l);
        u32 v3 = *((const u32*)(P + (size_t)p3 * HD) + l);
        if (e + 1 >= e1) v1 = 0;
        if (e + 2 >= e1) v2 = 0;
        if (e + 3 >= e1) v3 = 0;
        a0 += bflo(v0) + bflo(v1) + bflo(v2) + bflo(v3);
        a1 += bfhi(v0) + bfhi(v1) + bfhi(v2) + bfhi(v3);
      }
    }
    u32 hp = ((u32)f2bf(a1) << 16) | (u32)f2bf(a0);
    *(u32*)(Hs + swz((wr0 + i) * 256 + l * 4)) = hp;
  }

  const int lr = l & 15, lg = l >> 4;
  const int rloc = wr0;

  f32x4 zero = {0.f, 0.f, 0.f, 0.f};
  auto sweep = [&](const char* Ab, const u16* WT, f32x4* acc) {
    #pragma unroll
    for (int n = 0; n < 8; ++n) acc[n] = zero;
    #pragma unroll
    for (int k = 0; k < 4; ++k) {
      bf16x8 a = *(const bf16x8*)(Ab + swz((rloc + lr) * 256 + k * 64 + lg * 16));
      #pragma unroll
      for (int n = 0; n < 8; ++n) {
        bf16x8 b = *(const bf16x8*)(WT + (size_t)(n * 16 + lr) * HD + k * 32 + lg * 8);
        acc[n] = __builtin_amdgcn_mfma_f32_16x16x32_bf16(a, b, acc[n], 0, 0, 0);
      }
    }
  };

  f32x4 t1[8], t2[8], rg[8], nn[8];
  float bv[8];

  sweep(Xs, WgT + 0 * HD * HD, t1);
  sweep(Hs, WgT + 3 * HD * HD, t2);
  #pragma unroll
  for (int n = 0; n < 8; ++n) bv[n] = bir[n * 16 + lr];
  #pragma unroll
  for (int n = 0; n < 8; ++n)
    #pragma unroll
    for (int j = 0; j < 4; ++j) rg[n][j] = sigmoidf_(t1[n][j] + bv[n] + t2[n][j]);

  sweep(Hs, WgT + 5 * HD * HD, t2);
  #pragma unroll
  for (int n = 0; n < 8; ++n) bv[n] = bhn[n * 16 + lr];
  #pragma unroll
  for (int n = 0; n < 8; ++n)
    #pragma unroll
    for (int j = 0; j < 4; ++j) rg[n][j] *= (t2[n][j] + bv[n]);

  sweep(Xs, WgT + 2 * HD * HD, t1);
  #pragma unroll
  for (int n = 0; n < 8; ++n) bv[n] = bin_[n * 16 + lr];
  #pragma unroll
  for (int n = 0; n < 8; ++n)
    #pragma unroll
    for (int j = 0; j < 4; ++j) nn[n][j] = tanhf(t1[n][j] + bv[n] + rg[n][j]);

  sweep(Xs, WgT + 1 * HD * HD, t1);
  sweep(Hs, WgT + 4 * HD * HD, t2);
  #pragma unroll
  for (int n = 0; n < 8; ++n) bv[n] = biz[n * 16 + lr];
  #pragma unroll
  for (int n = 0; n < 8; ++n) {
    #pragma unroll
    for (int j = 0; j < 4; ++j) {
      int row = row0 + rloc + lg * 4 + j;
      if (row < N) {
        float z = sigmoidf_(t1[n][j] + bv[n] + t2[n][j]);
        u16 hu = *(const u16*)(Hs + swz((rloc + lg * 4 + j) * 256 + (n * 16 + lr) * 2));
        float h = __uint_as_float((u32)hu << 16);
        out[(size_t)row * HD + n * 16 + lr] = (1.0f - z) * nn[n][j] + z * h;
      }
    }
  }
}

// ============ Lowest-tier fallback: atomic scatter + f32-agg GRU ============
__global__ __launch_bounds__(256) void k_scatter(
    const u16* __restrict__ P, const int* __restrict__ src,
    const int* __restrict__ dst, const int* __restrict__ typ,
    const int* __restrict__ nePtr, float* __restrict__ agg,
    int ldP, int fixedType)
{
  const int ne = nePtr[0];
  const int lane = threadIdx.x & 63;
  const int wid = (int)((blockIdx.x * blockDim.x + threadIdx.x) >> 6);
  const int nw = (int)((gridDim.x * blockDim.x) >> 6);
  for (int e = wid; e < ne; e += nw) {
    const int t = typ[e];
    if (fixedType >= 0 && t != fixedType) continue;
    const size_t po = (ldP == HD) ? (size_t)src[e] * HD
                                  : (size_t)src[e] * (NT * HD) + (size_t)t * HD;
    u32 v = *(const u32*)(P + po + lane * 2);
    float* o = agg + (size_t)dst[e] * HD + lane * 2;
    unsafeAtomicAdd(o, bflo(v));
    unsafeAtomicAdd(o + 1, bfhi(v));
  }
}

__global__ __launch_bounds__(256) void k_gru(
    const float* __restrict__ X, const float* __restrict__ agg,
    const u16* __restrict__ WgT,
    const float* __restrict__ bir, const float* __restrict__ biz,
    const float* __restrict__ bin_, const float* __restrict__ bhn,
    float* __restrict__ out, int N)
{
  __shared__ char Xs[16384];
  __shared__ char Hs[16384];
  const int tid = threadIdx.x;
  const int row0 = blockIdx.x * 64;

  #pragma unroll
  for (int i = 0; i < 4; ++i) {
    int p = i * 4096 + tid * 16;
    int row = row0 + (p >> 8);
    union { u16 u[8]; bf16x8 v; } rx, rh;
    if (row < N) {
      const float4* sx = (const float4*)(X + (size_t)row0 * HD + (p >> 1));
      const float4* sh = (const float4*)(agg + (size_t)row0 * HD + (p >> 1));
      float4 x0 = sx[0], x1 = sx[1], h0 = sh[0], h1 = sh[1];
      rx.u[0] = f2bf(x0.x); rx.u[1] = f2bf(x0.y); rx.u[2] = f2bf(x0.z); rx.u[3] = f2bf(x0.w);
      rx.u[4] = f2bf(x1.x); rx.u[5] = f2bf(x1.y); rx.u[6] = f2bf(x1.z); rx.u[7] = f2bf(x1.w);
      rh.u[0] = f2bf(h0.x); rh.u[1] = f2bf(h0.y); rh.u[2] = f2bf(h0.z); rh.u[3] = f2bf(h0.w);
      rh.u[4] = f2bf(h1.x); rh.u[5] = f2bf(h1.y); rh.u[6] = f2bf(h1.z); rh.u[7] = f2bf(h1.w);
    } else {
      #pragma unroll
      for (int j = 0; j < 8; ++j) { rx.u[j] = 0; rh.u[j] = 0; }
    }
    *(bf16x8*)(Xs + swz(p)) = rx.v;
    *(bf16x8*)(Hs + swz(p)) = rh.v;
  }
  __syncthreads();

  const int l = tid & 63, w = tid >> 6;
  const int lr = l & 15, lg = l >> 4;
  const int rloc = w * 16;

  f32x4 zero = {0.f, 0.f, 0.f, 0.f};
  auto sweep = [&](const char* Ab, const u16* WT, f32x4* acc) {
    #pragma unroll
    for (int n = 0; n < 8; ++n) acc[n] = zero;
    #pragma unroll
    for (int k = 0; k < 4; ++k) {
      bf16x8 a = *(const bf16x8*)(Ab + swz((rloc + lr) * 256 + k * 64 + lg * 16));
      #pragma unroll
      for (int n = 0; n < 8; ++n) {
        bf16x8 b = *(const bf16x8*)(WT + (size_t)(n * 16 + lr) * HD + k * 32 + lg * 8);
        acc[n] = __builtin_amdgcn_mfma_f32_16x16x32_bf16(a, b, acc[n], 0, 0, 0);
      }
    }
  };

  f32x4 t1[8], t2[8], rg[8], nn[8];
  float bv[8];

  sweep(Xs, WgT + 0 * HD * HD, t1);
  sweep(Hs, WgT + 3 * HD * HD, t2);
  #pragma unroll
  for (int n = 0; n < 8; ++n) bv[n] = bir[n * 16 + lr];
  #pragma unroll
  for (int n = 0; n < 8; ++n)
    #pragma unroll
    for (int j = 0; j < 4; ++j) rg[n][j] = sigmoidf_(t1[n][j] + bv[n] + t2[n][j]);

  sweep(Hs, WgT + 5 * HD * HD, t2);
  #pragma unroll
  for (int n = 0; n < 8; ++n) bv[n] = bhn[n * 16 + lr];
  #pragma unroll
  for (int n = 0; n < 8; ++n)
    #pragma unroll
    for (int j = 0; j < 4; ++j) rg[n][j] *= (t2[n][j] + bv[n]);

  sweep(Xs, WgT + 2 * HD * HD, t1);
  #pragma unroll
  for (int n = 0; n < 8; ++n) bv[n] = bin_[n * 16 + lr];
  #pragma unroll
  for (int n = 0; n < 8; ++n)
    #pragma unroll
    for (int j = 0; j < 4; ++j) nn[n][j] = tanhf(t1[n][j] + bv[n] + rg[n][j]);

  sweep(Xs, WgT + 1 * HD * HD, t1);
  sweep(Hs, WgT + 4 * HD * HD, t2);
  #pragma unroll
  for (int n = 0; n < 8; ++n) bv[n] = biz[n * 16 + lr];
  #pragma unroll
  for (int n = 0; n < 8; ++n) {
    #pragma unroll
    for (int j = 0; j < 4; ++j) {
      int row = row0 + rloc + lg * 4 + j;
      if (row < N) {
        float z = sigmoidf_(t1[n][j] + bv[n] + t2[n][j]);
        float h = agg[(size_t)row * HD + n * 16 + lr];
        out[(size_t)row * HD + n * 16 + lr] = (1.0f - z) * nn[n][j] + z * h;
      }
    }
  }
}

extern "C" void kernel_launch(void* const* d_in, const int* in_sizes, int n_in,
                              void* d_out, int out_size, void* d_ws, size_t ws_size,
                              hipStream_t stream) {
  const float* X      = (const float*)d_in[0];
  const float* W_edge = (const float*)d_in[1];
  const float* b_edge = (const float*)d_in[2];
  const float* b_ir   = (const float*)d_in[4];
  const float* b_iz   = (const float*)d_in[6];
  const float* b_in   = (const float*)d_in[8];
  const float* b_hn   = (const float*)d_in[12];
  const int* src      = (const int*)d_in[13];
  const int* dst      = (const int*)d_in[14];
  const int* typ      = (const int*)d_in[15];
  const int* nePtr    = (const int*)d_in[16];

  const int N = in_sizes[0] / HD;
  const int E = in_sizes[13];
  char* ws = (char*)d_ws;

  size_t cur = 0;
  auto alloc = [&](size_t bytes) {
    size_t p = cur;
    cur = (cur + bytes + 255) & ~(size_t)255;
    return p;
  };
  u16* WeT   = (u16*)(ws + alloc((size_t)NT * HD * HD * 2));
  u16* WgT   = (u16*)(ws + alloc((size_t)6 * HD * HD * 2));
  int* deg   = (int*)(ws + alloc((size_t)N * 4));
  int* offA  = (int*)(ws + alloc((size_t)N * 4));
  int* bsum  = (int*)(ws + alloc(1024 * 4));
  u32* elist = (u32*)(ws + alloc((size_t)E * 4));
  size_t base_need = cur;
  u16* P     = (u16*)(ws + alloc((size_t)N * NT * HD * 2));
  const size_t csr_need = cur;
  u16* Hb    = (u16*)(ws + alloc((size_t)N * HD * 2));
  const size_t split_need = cur;

  const int gb = (N + 127) / 128;
  const int NB = (N + 1023) / 1024;

  k_cvt_w<<<(NT * HD * HD + 6 * HD * HD + 255) / 256, 256, 0, stream>>>(
      W_edge, (const float*)d_in[3], (const float*)d_in[5], (const float*)d_in[7],
      (const float*)d_in[9], (const float*)d_in[10], (const float*)d_in[11], WeT, WgT);

  if (ws_size >= csr_need) {
    hipMemsetAsync(deg, 0, (size_t)N * 4, stream);
    k_gemm_edge6<<<gb, 256, 0, stream>>>(X, WeT, b_edge, P, N);
    k_count<<<1024, 256, 0, stream>>>(dst, nePtr, deg);
    k_scan_a<<<NB, 256, 0, stream>>>(deg, offA, bsum, N);
    k_scan_b<<<1, 1024, 0, stream>>>(bsum, NB);
    k_scan_c<<<NB, 256, 0, stream>>>(offA, bsum, N);
    k_fill<<<1024, 256, 0, stream>>>(src, dst, typ, nePtr, offA, elist);
    if (ws_size >= split_need) {
      k_gather<<<(N + 3) / 4, 256, 0, stream>>>(P, deg, offA, elist, Hb, N);
      k_gru2<<<(N + 63) / 64, 256, 0, stream>>>(
          X, Hb, WgT, b_ir, b_iz, b_in, b_hn, (float*)d_out, N);
    } else {
      k_gather_gru<<<(N + 63) / 64, 256, 0, stream>>>(
          X, P, deg, offA, elist, WgT, b_ir, b_iz, b_in, b_hn, (float*)d_out, N);
    }
  } else {
    float* agg = (float*)d_out;
    hipMemsetAsync(d_out, 0, (size_t)out_size * sizeof(float), stream);
    size_t pneed = base_need + (size_t)N * NT * HD * 2;
    if (ws_size >= pneed) {
      u16* Pf = (u16*)(ws + base_need);
      k_gemm_edge6<<<gb, 256, 0, stream>>>(X, WeT, b_edge, Pf, N);
      k_scatter<<<2048, 256, 0, stream>>>(Pf, src, dst, typ, nePtr, agg, NT * HD, -1);
      k_gru<<<(N + 63) / 64, 256, 0, stream>>>(X, agg, WgT, b_ir, b_iz, b_in, b_hn, agg, N);
    }
  }
}

// Round 6
// 253.613 us; speedup vs baseline: 5.6424x; 1.0843x over previous
//
#include <hip/hip_runtime.h>
#include <hip/hip_bf16.h>

#define HD 128
#define NT 6

typedef unsigned short u16;
typedef unsigned int u32;
typedef __attribute__((ext_vector_type(8))) short bf16x8;
typedef __attribute__((ext_vector_type(4))) float f32x4;

__device__ __forceinline__ float sigmoidf_(float x) {
  return 1.0f / (1.0f + __expf(-x));
}

// f32 -> bf16 (RNE)
__device__ __forceinline__ u16 f2bf(float x) {
  u32 u = __float_as_uint(x);
  return (u16)((u + 0x7FFFu + ((u >> 16) & 1u)) >> 16);
}
__device__ __forceinline__ float bflo(u32 v) { return __uint_as_float(v << 16); }
__device__ __forceinline__ float bfhi(u32 v) { return __uint_as_float(v & 0xffff0000u); }

// XOR swizzle for 256B-row bf16 LDS tiles (involution, both sides).
__device__ __forceinline__ int swz(int p) { return p ^ (((p >> 8) & 7) << 4); }

// ============ weight convert+transpose: W^T bf16 ============
__global__ void k_cvt_w(const float* __restrict__ We,
                        const float* __restrict__ Wir, const float* __restrict__ Wiz,
                        const float* __restrict__ Win, const float* __restrict__ Whr,
                        const float* __restrict__ Whz, const float* __restrict__ Whn,
                        u16* __restrict__ WeT, u16* __restrict__ WgT) {
  int i = blockIdx.x * blockDim.x + threadIdx.x;
  if (i < NT * HD * HD) {
    int c = i >> 7, k = i & 127;                 // WeT[c][k] = We[k][c]
    WeT[i] = f2bf(We[(size_t)k * (NT * HD) + c]);
  } else {
    int j = i - NT * HD * HD;
    if (j < 6 * HD * HD) {
      int m = j >> 14, jj = j & 16383;
      int c = jj >> 7, k = jj & 127;
      const float* W = (m == 0) ? Wir : (m == 1) ? Wiz : (m == 2) ? Win
                     : (m == 3) ? Whr : (m == 4) ? Whz : Whn;
      WgT[j] = f2bf(W[(size_t)k * HD + c]);
    }
  }
}

// ============ Edge projection GEMM, all 6 types per block ============
__global__ __launch_bounds__(256) void k_gemm_edge6(
    const float* __restrict__ X, const u16* __restrict__ WeT,
    const float* __restrict__ Be, u16* __restrict__ P, int N)
{
  __shared__ char As[32768];   // 128 rows x 128 k bf16 (swizzled)
  __shared__ char Bs[32768];
  const int tid = threadIdx.x;
  const int row0 = blockIdx.x * 128;

  #pragma unroll
  for (int i = 0; i < 8; ++i) {
    int p = i * 4096 + tid * 16;
    int row = row0 + (p >> 8);
    union { u16 u[8]; bf16x8 v; } ra;
    if (row < N) {
      const float4* s = (const float4*)(X + (size_t)row0 * HD + (p >> 1));
      float4 f0 = s[0], f1 = s[1];
      ra.u[0] = f2bf(f0.x); ra.u[1] = f2bf(f0.y); ra.u[2] = f2bf(f0.z); ra.u[3] = f2bf(f0.w);
      ra.u[4] = f2bf(f1.x); ra.u[5] = f2bf(f1.y); ra.u[6] = f2bf(f1.z); ra.u[7] = f2bf(f1.w);
    } else {
      #pragma unroll
      for (int j = 0; j < 8; ++j) ra.u[j] = 0;
    }
    *(bf16x8*)(As + swz(p)) = ra.v;
  }

  const int l = tid & 63, w = tid >> 6;
  const int m0 = (w >> 1) * 64, n0 = (w & 1) * 64;
  const int lr = l & 15, lg = l >> 4;
  f32x4 zero = {0.f, 0.f, 0.f, 0.f};

  for (int t = 0; t < NT; ++t) {
    __syncthreads();
    const char* gB = (const char*)(WeT + (size_t)t * HD * HD);
    #pragma unroll
    for (int i = 0; i < 8; ++i) {
      int p = i * 4096 + tid * 16;
      *(bf16x8*)(Bs + swz(p)) = *(const bf16x8*)(gB + p);
    }
    __syncthreads();

    f32x4 acc[4][4];
    #pragma unroll
    for (int m = 0; m < 4; ++m)
      #pragma unroll
      for (int n = 0; n < 4; ++n) acc[m][n] = zero;

    #pragma unroll
    for (int k = 0; k < 4; ++k) {
      bf16x8 a[4], b[4];
      #pragma unroll
      for (int m = 0; m < 4; ++m)
        a[m] = *(const bf16x8*)(As + swz((m0 + m * 16 + lr) * 256 + k * 64 + lg * 16));
      #pragma unroll
      for (int n = 0; n < 4; ++n)
        b[n] = *(const bf16x8*)(Bs + swz((n0 + n * 16 + lr) * 256 + k * 64 + lg * 16));
      #pragma unroll
      for (int m = 0; m < 4; ++m)
        #pragma unroll
        for (int n = 0; n < 4; ++n)
          acc[m][n] = __builtin_amdgcn_mfma_f32_16x16x32_bf16(a[m], b[n], acc[m][n], 0, 0, 0);
    }

    float bias[4];
    #pragma unroll
    for (int n = 0; n < 4; ++n) bias[n] = Be[t * HD + n0 + n * 16 + lr];
    #pragma unroll
    for (int m = 0; m < 4; ++m) {
      int rbase = row0 + m0 + m * 16 + lg * 4;
      #pragma unroll
      for (int j = 0; j < 4; ++j) {
        int row = rbase + j;
        if (row < N) {
          #pragma unroll
          for (int n = 0; n < 4; ++n)
            P[(size_t)row * (NT * HD) + t * HD + n0 + n * 16 + lr] =
                f2bf(acc[m][n][j] + bias[n]);
        }
      }
    }
  }
}

// ============ CSR build ============
__global__ __launch_bounds__(256) void k_count(const int* __restrict__ dst,
                                               const int* __restrict__ nePtr,
                                               int* __restrict__ deg) {
  const int ne = nePtr[0];
  for (int e = blockIdx.x * blockDim.x + threadIdx.x; e < ne;
       e += gridDim.x * blockDim.x)
    atomicAdd(&deg[dst[e]], 1);
}

__global__ __launch_bounds__(256) void k_scan_a(const int* __restrict__ deg,
                                                int* __restrict__ off,
                                                int* __restrict__ bsum, int N) {
  __shared__ int s[256];
  const int b = blockIdx.x, tid = threadIdx.x;
  const int base = b * 1024 + tid * 4;
  int v0 = 0, v1 = 0, v2 = 0, v3 = 0;
  if (base < N) v0 = deg[base];
  if (base + 1 < N) v1 = deg[base + 1];
  if (base + 2 < N) v2 = deg[base + 2];
  if (base + 3 < N) v3 = deg[base + 3];
  const int sum = v0 + v1 + v2 + v3;
  s[tid] = sum;
  __syncthreads();
  for (int d = 1; d < 256; d <<= 1) {
    int t = (tid >= d) ? s[tid - d] : 0;
    __syncthreads();
    s[tid] += t;
    __syncthreads();
  }
  const int excl = s[tid] - sum;
  if (base < N) off[base] = excl;
  if (base + 1 < N) off[base + 1] = excl + v0;
  if (base + 2 < N) off[base + 2] = excl + v0 + v1;
  if (base + 3 < N) off[base + 3] = excl + v0 + v1 + v2;
  if (tid == 255) bsum[b] = s[255];
}

__global__ void k_scan_b(int* __restrict__ bsum, int nb) {
  __shared__ int s[1024];
  const int tid = threadIdx.x;
  const int v = (tid < nb) ? bsum[tid] : 0;
  s[tid] = v;
  __syncthreads();
  for (int d = 1; d < 1024; d <<= 1) {
    int t = (tid >= d) ? s[tid - d] : 0;
    __syncthreads();
    s[tid] += t;
    __syncthreads();
  }
  if (tid < nb) bsum[tid] = s[tid] - v;   // exclusive
}

__global__ __launch_bounds__(256) void k_scan_c(int* __restrict__ off,
                                                const int* __restrict__ bsum, int N) {
  const int b = blockIdx.x, tid = threadIdx.x;
  const int add = bsum[b];
  const int base = b * 1024 + tid * 4;
  #pragma unroll
  for (int i = 0; i < 4; ++i)
    if (base + i < N) off[base + i] += add;
}

__global__ __launch_bounds__(256) void k_fill(const int* __restrict__ src,
                                              const int* __restrict__ dst,
                                              const int* __restrict__ typ,
                                              const int* __restrict__ nePtr,
                                              int* __restrict__ off,
                                              u32* __restrict__ elist) {
  const int ne = nePtr[0];
  for (int e = blockIdx.x * blockDim.x + threadIdx.x; e < ne;
       e += gridDim.x * blockDim.x) {
    int pos = atomicAdd(&off[dst[e]], 1);
    elist[pos] = (u32)(src[e] * NT + typ[e]);   // P-row index
  }
}

// ============ Standalone gather: one wave per node, masked 4-deep MLP ============
__global__ __launch_bounds__(256) void k_gather(
    const u16* __restrict__ P, const int* __restrict__ deg,
    const int* __restrict__ off, const u32* __restrict__ elist,
    u16* __restrict__ Hb, int N)
{
  const int l = threadIdx.x & 63;
  int wid = (int)((blockIdx.x * blockDim.x + threadIdx.x) >> 6);
  int nw = (int)((gridDim.x * blockDim.x) >> 6);
  for (int n = wid; n < N; n += nw) {
    const int e1 = off[n];
    const int e0 = e1 - deg[n];
    float a0 = 0.f, a1 = 0.f, b0 = 0.f, b1 = 0.f;
    for (int e = e0; e < e1; e += 4) {
      u32 p0 = elist[e];
      u32 p1 = (e + 1 < e1) ? elist[e + 1] : p0;
      u32 p2 = (e + 2 < e1) ? elist[e + 2] : p0;
      u32 p3 = (e + 3 < e1) ? elist[e + 3] : p0;
      u32 v0 = *((const u32*)(P + (size_t)p0 * HD) + l);
      u32 v1 = *((const u32*)(P + (size_t)p1 * HD) + l);
      u32 v2 = *((const u32*)(P + (size_t)p2 * HD) + l);
      u32 v3 = *((const u32*)(P + (size_t)p3 * HD) + l);
      if (e + 1 >= e1) v1 = 0;
      if (e + 2 >= e1) v2 = 0;
      if (e + 3 >= e1) v3 = 0;
      a0 += bflo(v0); a1 += bfhi(v0);
      b0 += bflo(v1); b1 += bfhi(v1);
      a0 += bflo(v2); a1 += bfhi(v2);
      b0 += bflo(v3); b1 += bfhi(v3);
    }
    a0 += b0; a1 += b1;
    u32 hp = ((u32)f2bf(a1) << 16) | (u32)f2bf(a0);
    *((u32*)(Hb + (size_t)n * HD) + l) = hp;
  }
}

// ============ GRU v3: 8 waves, 128-row tile, double-buffered W staging ============
__global__ __launch_bounds__(512, 2) void k_gru3(
    const float* __restrict__ X, const u16* __restrict__ Hb,
    const u16* __restrict__ WgT,   // 6x[128][128] W^T: ir,iz,in,hr,hz,hn
    const float* __restrict__ bir, const float* __restrict__ biz,
    const float* __restrict__ bin_, const float* __restrict__ bhn,
    float* __restrict__ out, int N)
{
  __shared__ char Xs[32768];     // 128 rows x 128 k bf16 (swizzled)
  __shared__ char Hs[32768];
  __shared__ char Wb[2][32768];  // double-buffered gate W^T
  const int tid = threadIdx.x;
  const int row0 = blockIdx.x * 128;
  const int l = tid & 63, w = tid >> 6;
  const int lr = l & 15, lg = l >> 4;
  const int rloc = w * 16;

  // ---- stage X (f32->bf16) and Hb (bf16 copy) tiles ----
  #pragma unroll
  for (int i = 0; i < 4; ++i) {
    int p = i * 8192 + tid * 16;
    int row = row0 + (p >> 8);
    union { u16 u[8]; bf16x8 v; } rx, rh;
    if (row < N) {
      const float4* sx = (const float4*)(X + (size_t)row0 * HD + (p >> 1));
      float4 x0 = sx[0], x1 = sx[1];
      rx.u[0] = f2bf(x0.x); rx.u[1] = f2bf(x0.y); rx.u[2] = f2bf(x0.z); rx.u[3] = f2bf(x0.w);
      rx.u[4] = f2bf(x1.x); rx.u[5] = f2bf(x1.y); rx.u[6] = f2bf(x1.z); rx.u[7] = f2bf(x1.w);
      rh.v = *(const bf16x8*)((const char*)Hb + (size_t)row0 * 256 + p);
    } else {
      #pragma unroll
      for (int j = 0; j < 8; ++j) { rx.u[j] = 0; rh.u[j] = 0; }
    }
    *(bf16x8*)(Xs + swz(p)) = rx.v;
    *(bf16x8*)(Hs + swz(p)) = rh.v;
  }

  // ---- W register staging (64B/thread) ----
  bf16x8 wreg[4];
  auto loadW = [&](int g) {
    const char* gp = (const char*)(WgT + (size_t)g * HD * HD);
    #pragma unroll
    for (int i = 0; i < 4; ++i)
      wreg[i] = *(const bf16x8*)(gp + i * 8192 + tid * 16);
  };
  auto writeW = [&](int buf) {
    #pragma unroll
    for (int i = 0; i < 4; ++i) {
      int p = i * 8192 + tid * 16;
      *(bf16x8*)(Wb[buf] + swz(p)) = wreg[i];
    }
  };

  f32x4 zero = {0.f, 0.f, 0.f, 0.f};
  auto sweepL = [&](const char* Ab, const char* Wp, f32x4* acc) {
    #pragma unroll
    for (int n = 0; n < 8; ++n) acc[n] = zero;
    #pragma unroll
    for (int k = 0; k < 4; ++k) {
      bf16x8 a = *(const bf16x8*)(Ab + swz((rloc + lr) * 256 + k * 64 + lg * 16));
      #pragma unroll
      for (int n = 0; n < 8; ++n) {
        bf16x8 b = *(const bf16x8*)(Wp + swz((n * 16 + lr) * 256 + k * 64 + lg * 16));
        acc[n] = __builtin_amdgcn_mfma_f32_16x16x32_bf16(a, b, acc[n], 0, 0, 0);
      }
    }
  };

  f32x4 t1[8], t2[8], rg[8], nn[8];
  float bv[8];

  // prologue: stage Wir into buf0
  loadW(0); writeW(0);
  __syncthreads();

  // s0: t1 = X @ Wir          (preload Whr)
  loadW(3);
  sweepL(Xs, Wb[0], t1);
  writeW(1);
  __syncthreads();

  // s1: t2 = H @ Whr          (preload Whn) -> r
  loadW(5);
  sweepL(Hs, Wb[1], t2);
  writeW(0);
  #pragma unroll
  for (int n = 0; n < 8; ++n) bv[n] = bir[n * 16 + lr];
  #pragma unroll
  for (int n = 0; n < 8; ++n)
    #pragma unroll
    for (int j = 0; j < 4; ++j) rg[n][j] = sigmoidf_(t1[n][j] + bv[n] + t2[n][j]);
  __syncthreads();

  // s2: t2 = H @ Whn          (preload Win) -> rn
  loadW(2);
  sweepL(Hs, Wb[0], t2);
  writeW(1);
  #pragma unroll
  for (int n = 0; n < 8; ++n) bv[n] = bhn[n * 16 + lr];
  #pragma unroll
  for (int n = 0; n < 8; ++n)
    #pragma unroll
    for (int j = 0; j < 4; ++j) rg[n][j] *= (t2[n][j] + bv[n]);
  __syncthreads();

  // s3: t1 = X @ Win          (preload Wiz) -> n
  loadW(1);
  sweepL(Xs, Wb[1], t1);
  writeW(0);
  #pragma unroll
  for (int n = 0; n < 8; ++n) bv[n] = bin_[n * 16 + lr];
  #pragma unroll
  for (int n = 0; n < 8; ++n)
    #pragma unroll
    for (int j = 0; j < 4; ++j) nn[n][j] = tanhf(t1[n][j] + bv[n] + rg[n][j]);
  __syncthreads();

  // s4: t1 = X @ Wiz          (preload Whz)
  loadW(4);
  sweepL(Xs, Wb[0], t1);
  writeW(1);
  __syncthreads();

  // s5: t2 = H @ Whz -> z, out
  sweepL(Hs, Wb[1], t2);
  #pragma unroll
  for (int n = 0; n < 8; ++n) bv[n] = biz[n * 16 + lr];
  #pragma unroll
  for (int n = 0; n < 8; ++n) {
    #pragma unroll
    for (int j = 0; j < 4; ++j) {
      int row = row0 + rloc + lg * 4 + j;
      if (row < N) {
        int col = n * 16 + lr;
        float z = sigmoidf_(t1[n][j] + bv[n] + t2[n][j]);
        u16 hu = Hb[(size_t)row * HD + col];            // L3-hot, coalesced
        float h = __uint_as_float((u32)hu << 16);
        out[(size_t)row * HD + col] = (1.0f - z) * nn[n][j] + z * h;
      }
    }
  }
}

// ============ Fused gather+GRU (mid-tier fallback) ============
__global__ __launch_bounds__(256) void k_gather_gru(
    const float* __restrict__ X, const u16* __restrict__ P,
    const int* __restrict__ deg, const int* __restrict__ off,
    const u32* __restrict__ elist, const u16* __restrict__ WgT,
    const float* __restrict__ bir, const float* __restrict__ biz,
    const float* __restrict__ bin_, const float* __restrict__ bhn,
    float* __restrict__ out, int N)
{
  __shared__ char Xs[16384];
  __shared__ char Hs[16384];
  const int tid = threadIdx.x;
  const int l = tid & 63, w = tid >> 6;
  const int row0 = blockIdx.x * 64;
  const int wr0 = w * 16;

  #pragma unroll
  for (int it = 0; it < 4; ++it) {
    int chunk = it * 64 + l;
    int r = chunk >> 4, seg = chunk & 15;
    int grow = row0 + wr0 + r;
    union { u16 u[8]; bf16x8 v; } rx;
    if (grow < N) {
      const float4* sx = (const float4*)(X + (size_t)grow * HD + seg * 8);
      float4 x0 = sx[0], x1 = sx[1];
      rx.u[0] = f2bf(x0.x); rx.u[1] = f2bf(x0.y); rx.u[2] = f2bf(x0.z); rx.u[3] = f2bf(x0.w);
      rx.u[4] = f2bf(x1.x); rx.u[5] = f2bf(x1.y); rx.u[6] = f2bf(x1.z); rx.u[7] = f2bf(x1.w);
    } else {
      #pragma unroll
      for (int j = 0; j < 8; ++j) rx.u[j] = 0;
    }
    *(bf16x8*)(Xs + swz((wr0 + r) * 256 + seg * 16)) = rx.v;
  }

  for (int i = 0; i < 16; ++i) {
    int n = row0 + wr0 + i;
    float a0 = 0.f, a1 = 0.f;
    if (n < N) {
      int e1 = off[n];
      for (int e = e1 - deg[n]; e < e1; e += 4) {
        u32 p0 = elist[e];
        u32 p1 = (e + 1 < e1) ? elist[e + 1] : p0;
        u32 p2 = (e + 2 < e1) ? elist[e + 2] : p0;
        u32 p3 = (e + 3 < e1) ? elist[e + 3] : p0;
        u32 v0 = *((const u32*)(P + (size_t)p0 * HD) + l);
        u32 v1 = *((const u32*)(P + (size_t)p1 * HD) + l);
        u32 v2 = *((const u32*)(P + (size_t)p2 * HD) + l);
        u32 v3 = *((const u32*)(P + (size_t)p3 * HD) + l);
        if (e + 1 >= e1) v1 = 0;
        if (e + 2 >= e1) v2 = 0;
        if (e + 3 >= e1) v3 = 0;
        a0 += bflo(v0) + bflo(v1) + bflo(v2) + bflo(v3);
        a1 += bfhi(v0) + bfhi(v1) + bfhi(v2) + bfhi(v3);
      }
    }
    u32 hp = ((u32)f2bf(a1) << 16) | (u32)f2bf(a0);
    *(u32*)(Hs + swz((wr0 + i) * 256 + l * 4)) = hp;
  }

  const int lr = l & 15, lg = l >> 4;
  const int rloc = wr0;

  f32x4 zero = {0.f, 0.f, 0.f, 0.f};
  auto sweep = [&](const char* Ab, const u16* WT, f32x4* acc) {
    #pragma unroll
    for (int n = 0; n < 8; ++n) acc[n] = zero;
    #pragma unroll
    for (int k = 0; k < 4; ++k) {
      bf16x8 a = *(const bf16x8*)(Ab + swz((rloc + lr) * 256 + k * 64 + lg * 16));
      #pragma unroll
      for (int n = 0; n < 8; ++n) {
        bf16x8 b = *(const bf16x8*)(WT + (size_t)(n * 16 + lr) * HD + k * 32 + lg * 8);
        acc[n] = __builtin_amdgcn_mfma_f32_16x16x32_bf16(a, b, acc[n], 0, 0, 0);
      }
    }
  };

  f32x4 t1[8], t2[8], rg[8], nn[8];
  float bv[8];

  sweep(Xs, WgT + 0 * HD * HD, t1);
  sweep(Hs, WgT + 3 * HD * HD, t2);
  #pragma unroll
  for (int n = 0; n < 8; ++n) bv[n] = bir[n * 16 + lr];
  #pragma unroll
  for (int n = 0; n < 8; ++n)
    #pragma unroll
    for (int j = 0; j < 4; ++j) rg[n][j] = sigmoidf_(t1[n][j] + bv[n] + t2[n][j]);

  sweep(Hs, WgT + 5 * HD * HD, t2);
  #pragma unroll
  for (int n = 0; n < 8; ++n) bv[n] = bhn[n * 16 + lr];
  #pragma unroll
  for (int n = 0; n < 8; ++n)
    #pragma unroll
    for (int j = 0; j < 4; ++j) rg[n][j] *= (t2[n][j] + bv[n]);

  sweep(Xs, WgT + 2 * HD * HD, t1);
  #pragma unroll
  for (int n = 0; n < 8; ++n) bv[n] = bin_[n * 16 + lr];
  #pragma unroll
  for (int n = 0; n < 8; ++n)
    #pragma unroll
    for (int j = 0; j < 4; ++j) nn[n][j] = tanhf(t1[n][j] + bv[n] + rg[n][j]);

  sweep(Xs, WgT + 1 * HD * HD, t1);
  sweep(Hs, WgT + 4 * HD * HD, t2);
  #pragma unroll
  for (int n = 0; n < 8; ++n) bv[n] = biz[n * 16 + lr];
  #pragma unroll
  for (int n = 0; n < 8; ++n) {
    #pragma unroll
    for (int j = 0; j < 4; ++j) {
      int row = row0 + rloc + lg * 4 + j;
      if (row < N) {
        float z = sigmoidf_(t1[n][j] + bv[n] + t2[n][j]);
        u16 hu = *(const u16*)(Hs + swz((rloc + lg * 4 + j) * 256 + (n * 16 + lr) * 2));
        float h = __uint_as_float((u32)hu << 16);
        out[(size_t)row * HD + n * 16 + lr] = (1.0f - z) * nn[n][j] + z * h;
      }
    }
  }
}

// ============ Lowest-tier fallback: atomic scatter + f32-agg GRU ============
__global__ __launch_bounds__(256) void k_scatter(
    const u16* __restrict__ P, const int* __restrict__ src,
    const int* __restrict__ dst, const int* __restrict__ typ,
    const int* __restrict__ nePtr, float* __restrict__ agg,
    int ldP, int fixedType)
{
  const int ne = nePtr[0];
  const int lane = threadIdx.x & 63;
  const int wid = (int)((blockIdx.x * blockDim.x + threadIdx.x) >> 6);
  const int nw = (int)((gridDim.x * blockDim.x) >> 6);
  for (int e = wid; e < ne; e += nw) {
    const int t = typ[e];
    if (fixedType >= 0 && t != fixedType) continue;
    const size_t po = (ldP == HD) ? (size_t)src[e] * HD
                                  : (size_t)src[e] * (NT * HD) + (size_t)t * HD;
    u32 v = *(const u32*)(P + po + lane * 2);
    float* o = agg + (size_t)dst[e] * HD + lane * 2;
    unsafeAtomicAdd(o, bflo(v));
    unsafeAtomicAdd(o + 1, bfhi(v));
  }
}

__global__ __launch_bounds__(256) void k_gru(
    const float* __restrict__ X, const float* __restrict__ agg,
    const u16* __restrict__ WgT,
    const float* __restrict__ bir, const float* __restrict__ biz,
    const float* __restrict__ bin_, const float* __restrict__ bhn,
    float* __restrict__ out, int N)
{
  __shared__ char Xs[16384];
  __shared__ char Hs[16384];
  const int tid = threadIdx.x;
  const int row0 = blockIdx.x * 64;

  #pragma unroll
  for (int i = 0; i < 4; ++i) {
    int p = i * 4096 + tid * 16;
    int row = row0 + (p >> 8);
    union { u16 u[8]; bf16x8 v; } rx, rh;
    if (row < N) {
      const float4* sx = (const float4*)(X + (size_t)row0 * HD + (p >> 1));
      const float4* sh = (const float4*)(agg + (size_t)row0 * HD + (p >> 1));
      float4 x0 = sx[0], x1 = sx[1], h0 = sh[0], h1 = sh[1];
      rx.u[0] = f2bf(x0.x); rx.u[1] = f2bf(x0.y); rx.u[2] = f2bf(x0.z); rx.u[3] = f2bf(x0.w);
      rx.u[4] = f2bf(x1.x); rx.u[5] = f2bf(x1.y); rx.u[6] = f2bf(x1.z); rx.u[7] = f2bf(x1.w);
      rh.u[0] = f2bf(h0.x); rh.u[1] = f2bf(h0.y); rh.u[2] = f2bf(h0.z); rh.u[3] = f2bf(h0.w);
      rh.u[4] = f2bf(h1.x); rh.u[5] = f2bf(h1.y); rh.u[6] = f2bf(h1.z); rh.u[7] = f2bf(h1.w);
    } else {
      #pragma unroll
      for (int j = 0; j < 8; ++j) { rx.u[j] = 0; rh.u[j] = 0; }
    }
    *(bf16x8*)(Xs + swz(p)) = rx.v;
    *(bf16x8*)(Hs + swz(p)) = rh.v;
  }
  __syncthreads();

  const int l = tid & 63, w = tid >> 6;
  const int lr = l & 15, lg = l >> 4;
  const int rloc = w * 16;

  f32x4 zero = {0.f, 0.f, 0.f, 0.f};
  auto sweep = [&](const char* Ab, const u16* WT, f32x4* acc) {
    #pragma unroll
    for (int n = 0; n < 8; ++n) acc[n] = zero;
    #pragma unroll
    for (int k = 0; k < 4; ++k) {
      bf16x8 a = *(const bf16x8*)(Ab + swz((rloc + lr) * 256 + k * 64 + lg * 16));
      #pragma unroll
      for (int n = 0; n < 8; ++n) {
        bf16x8 b = *(const bf16x8*)(WT + (size_t)(n * 16 + lr) * HD + k * 32 + lg * 8);
        acc[n] = __builtin_amdgcn_mfma_f32_16x16x32_bf16(a, b, acc[n], 0, 0, 0);
      }
    }
  };

  f32x4 t1[8], t2[8], rg[8], nn[8];
  float bv[8];

  sweep(Xs, WgT + 0 * HD * HD, t1);
  sweep(Hs, WgT + 3 * HD * HD, t2);
  #pragma unroll
  for (int n = 0; n < 8; ++n) bv[n] = bir[n * 16 + lr];
  #pragma unroll
  for (int n = 0; n < 8; ++n)
    #pragma unroll
    for (int j = 0; j < 4; ++j) rg[n][j] = sigmoidf_(t1[n][j] + bv[n] + t2[n][j]);

  sweep(Hs, WgT + 5 * HD * HD, t2);
  #pragma unroll
  for (int n = 0; n < 8; ++n) bv[n] = bhn[n * 16 + lr];
  #pragma unroll
  for (int n = 0; n < 8; ++n)
    #pragma unroll
    for (int j = 0; j < 4; ++j) rg[n][j] *= (t2[n][j] + bv[n]);

  sweep(Xs, WgT + 2 * HD * HD, t1);
  #pragma unroll
  for (int n = 0; n < 8; ++n) bv[n] = bin_[n * 16 + lr];
  #pragma unroll
  for (int n = 0; n < 8; ++n)
    #pragma unroll
    for (int j = 0; j < 4; ++j) nn[n][j] = tanhf(t1[n][j] + bv[n] + rg[n][j]);

  sweep(Xs, WgT + 1 * HD * HD, t1);
  sweep(Hs, WgT + 4 * HD * HD, t2);
  #pragma unroll
  for (int n = 0; n < 8; ++n) bv[n] = biz[n * 16 + lr];
  #pragma unroll
  for (int n = 0; n < 8; ++n) {
    #pragma unroll
    for (int j = 0; j < 4; ++j) {
      int row = row0 + rloc + lg * 4 + j;
      if (row < N) {
        float z = sigmoidf_(t1[n][j] + bv[n] + t2[n][j]);
        float h = agg[(size_t)row * HD + n * 16 + lr];
        out[(size_t)row * HD + n * 16 + lr] = (1.0f - z) * nn[n][j] + z * h;
      }
    }
  }
}

extern "C" void kernel_launch(void* const* d_in, const int* in_sizes, int n_in,
                              void* d_out, int out_size, void* d_ws, size_t ws_size,
                              hipStream_t stream) {
  const float* X      = (const float*)d_in[0];
  const float* W_edge = (const float*)d_in[1];
  const float* b_edge = (const float*)d_in[2];
  const float* b_ir   = (const float*)d_in[4];
  const float* b_iz   = (const float*)d_in[6];
  const float* b_in   = (const float*)d_in[8];
  const float* b_hn   = (const float*)d_in[12];
  const int* src      = (const int*)d_in[13];
  const int* dst      = (const int*)d_in[14];
  const int* typ      = (const int*)d_in[15];
  const int* nePtr    = (const int*)d_in[16];

  const int N = in_sizes[0] / HD;
  const int E = in_sizes[13];
  char* ws = (char*)d_ws;

  size_t cur = 0;
  auto alloc = [&](size_t bytes) {
    size_t p = cur;
    cur = (cur + bytes + 255) & ~(size_t)255;
    return p;
  };
  u16* WeT   = (u16*)(ws + alloc((size_t)NT * HD * HD * 2));
  u16* WgT   = (u16*)(ws + alloc((size_t)6 * HD * HD * 2));
  int* deg   = (int*)(ws + alloc((size_t)N * 4));
  int* offA  = (int*)(ws + alloc((size_t)N * 4));
  int* bsum  = (int*)(ws + alloc(1024 * 4));
  u32* elist = (u32*)(ws + alloc((size_t)E * 4));
  size_t base_need = cur;
  u16* P     = (u16*)(ws + alloc((size_t)N * NT * HD * 2));
  const size_t csr_need = cur;
  u16* Hb    = (u16*)(ws + alloc((size_t)N * HD * 2));
  const size_t split_need = cur;

  const int gb = (N + 127) / 128;
  const int NB = (N + 1023) / 1024;

  k_cvt_w<<<(NT * HD * HD + 6 * HD * HD + 255) / 256, 256, 0, stream>>>(
      W_edge, (const float*)d_in[3], (const float*)d_in[5], (const float*)d_in[7],
      (const float*)d_in[9], (const float*)d_in[10], (const float*)d_in[11], WeT, WgT);

  if (ws_size >= csr_need) {
    hipMemsetAsync(deg, 0, (size_t)N * 4, stream);
    k_gemm_edge6<<<gb, 256, 0, stream>>>(X, WeT, b_edge, P, N);
    k_count<<<1024, 256, 0, stream>>>(dst, nePtr, deg);
    k_scan_a<<<NB, 256, 0, stream>>>(deg, offA, bsum, N);
    k_scan_b<<<1, 1024, 0, stream>>>(bsum, NB);
    k_scan_c<<<NB, 256, 0, stream>>>(offA, bsum, N);
    k_fill<<<1024, 256, 0, stream>>>(src, dst, typ, nePtr, offA, elist);
    if (ws_size >= split_need) {
      k_gather<<<(N + 3) / 4, 256, 0, stream>>>(P, deg, offA, elist, Hb, N);
      k_gru3<<<gb, 512, 0, stream>>>(
          X, Hb, WgT, b_ir, b_iz, b_in, b_hn, (float*)d_out, N);
    } else {
      k_gather_gru<<<(N + 63) / 64, 256, 0, stream>>>(
          X, P, deg, offA, elist, WgT, b_ir, b_iz, b_in, b_hn, (float*)d_out, N);
    }
  } else {
    float* agg = (float*)d_out;
    hipMemsetAsync(d_out, 0, (size_t)out_size * sizeof(float), stream);
    size_t pneed = base_need + (size_t)N * NT * HD * 2;
    if (ws_size >= pneed) {
      u16* Pf = (u16*)(ws + base_need);
      k_gemm_edge6<<<gb, 256, 0, stream>>>(X, WeT, b_edge, Pf, N);
      k_scatter<<<2048, 256, 0, stream>>>(Pf, src, dst, typ, nePtr, agg, NT * HD, -1);
      k_gru<<<(N + 63) / 64, 256, 0, stream>>>(X, agg, WgT, b_ir, b_iz, b_in, b_hn, agg, N);
    }
  }
}